// Round 2
// baseline (1251.663 us; speedup 1.0000x reference)
//
#include <hip/hip_runtime.h>
#include <stdint.h>
#include <math.h>

typedef unsigned long long u64;
typedef unsigned int u32;
typedef float float4a __attribute__((ext_vector_type(4), aligned(4)));

// ---------------- workspace layout (bytes) ----------------
static const size_t OFF_CTL   = 0;          // [0]=u64 prefix/kstar, [8]=u32 target, [12]=u32 count
static const size_t OFF_HIST  = 1024;       // 8 passes * 256 * 4 = 8 KB
static const size_t OFF_DOTS  = 1049600;    // 16384*54*4
static const size_t OFF_WCV   = 4588544;    // 589824*4  [tap][ic][oc]
static const size_t OFF_XD    = 6947840;    // 16384*256*4 (conv out f32, HWC)
static const size_t OFF_BOX   = 23725056;   // 147456*16 (float4)
static const size_t OFF_KEYS  = 26084352;   // 147456*8
static const size_t OFF_CKEY  = 27264000;   // 6144*8
static const size_t OFF_CIDX  = 27313152;   // 6144*4
static const size_t OFF_TB    = 27337728;   // 6000*16
static const size_t OFF_TSC   = 27433728;   // 6000*4
static const size_t OFF_ALIVE = 27458048;   // 128*8
static const size_t OFF_MASK  = 27459072;   // 6000*96*8 = 4608000
static const size_t OFF_FPAD  = 32067584;   // 256*130*132*4 = 17571840  end ~49.6 MB

// XLA-CPU / Eigen / Cephes f32 exp (FMA form) — bit-matches the np reference.
__device__ __forceinline__ float exp_xla(float x) {
    float m = floorf(__fmaf_rn(x, 1.44269504088896341f, 0.5f));
    float r = __fmaf_rn(m, -0.693359375f, x);
    r = __fmaf_rn(m, 2.12194440e-4f, r);
    float r2 = r * r;
    float p = 1.9875691500e-4f;
    p = __fmaf_rn(p, r, 1.3981999507e-3f);
    p = __fmaf_rn(p, r, 8.3334519073e-3f);
    p = __fmaf_rn(p, r, 4.1665795894e-2f);
    p = __fmaf_rn(p, r, 1.6666665459e-1f);
    p = __fmaf_rn(p, r, 5.0000001201e-1f);
    p = __fmaf_rn(p, r2, r);
    p = __fadd_rn(p, 1.0f);
    int mi = (int)m;
    return p * __int_as_float((mi + 127) << 23);
}

// async global->LDS, 16B per lane, wave-uniform LDS base + lane*16
__device__ __forceinline__ void gload_lds16(const void* g, void* l) {
    __builtin_amdgcn_global_load_lds(
        (const __attribute__((address_space(1))) void*)g,
        (__attribute__((address_space(3))) void*)l, 16, 0, 0);
}

// ---------------- weight prep: rpn_w [oc][ic][tap] -> f32 [tap][ic][oc] ------
__global__ void prep_wcv(const float* __restrict__ rpn_w, float* __restrict__ wcv) {
    int t = blockIdx.x * 256 + threadIdx.x;
    if (t >= 589824) return;
    int tap = t / 65536, rem = t % 65536, ic = rem / 256, oc = rem % 256;
    wcv[t] = rpn_w[oc * 2304 + ic * 9 + tap];
}

// ---------------- feature pad: featP[ic][130][132], +1 halo of literal zeros -
__global__ void prep_pad(const float* __restrict__ feat, float* __restrict__ featP) {
    int t = blockIdx.x * 256 + threadIdx.x;
    if (t >= 256 * 130 * 132) return;
    int ic = t / 17160, rem = t % 17160, y = rem / 132, x = rem % 132;
    int sy = y - 1, sx = x - 1;
    float v = 0.f;
    if (sy >= 0 && sy < 128 && sx >= 0 && sx < 128)
        v = feat[ic * 16384 + sy * 128 + sx];
    featP[t] = v;
}

// ---------------- conv3x3 v2: 4px x 4oc per thread, 1024 blocks --------------
// Occupancy was grid-limited (512 blocks = 2 blocks/CU = 2 waves/SIMD ->
// VALUBusy 38.8%). Re-tile: 16-oc blocks, 4px/thread -> 1024 blocks,
// 4 waves/SIMD, sW 16 KB. Per-output FMA chain is UNCHANGED (one f32 acc,
// k=(tap, ic 0..255) ascending, __fmaf_rn) -> bit-exact.
__global__ __launch_bounds__(256, 4) void conv3x3(const float* __restrict__ featP,
                                                  const float* __restrict__ wcv,
                                                  const float* __restrict__ rpn_b,
                                                  float* __restrict__ xd) {
    __shared__ float sW[4096];                 // [ic][16 oc] for current tap
    const int band = blockIdx.x & 7;           // tile row (XCD-pinned)
    const int rest = blockIdx.x >> 3;          // 0..127
    const int tx = rest & 7, ocb = rest >> 3;  // tile col, oc-block(16)
    const int oc0 = ocb * 16;
    const int tid = threadIdx.x;
    const int ocg = tid >> 6;                  // wave id 0..3 -> 4 oc each
    const int lane = tid & 63;
    const int py = lane >> 2, px0 = (lane & 3) * 4;   // wave covers 16x16 tile
    const int gy = band * 16 + py, gx0 = tx * 16 + px0;
    const int ocB = oc0 + ocg * 4;
    float acc[4][4];
#pragma unroll
    for (int p = 0; p < 4; ++p)
#pragma unroll
        for (int o = 0; o < 4; ++o) acc[p][o] = 0.f;
#pragma unroll
    for (int tap = 0; tap < 9; ++tap) {        // k-major: tap (ky,kx)
        __syncthreads();
        for (int idx = tid; idx < 4096; idx += 256)
            sW[idx] = wcv[tap * 65536 + (idx >> 4) * 256 + oc0 + (idx & 15)];
        __syncthreads();
        const float* fp = featP + (size_t)(gy + tap / 3) * 132 + (gx0 + tap % 3);
        const float* wl = sW + ocg * 4;
        for (int ic = 0; ic < 256; ++ic) {     // k-minor: ic ascending
            float4a fA = *(const float4a*)(fp + (size_t)ic * 17160);
            float4a w4 = *(const float4a*)(wl + ic * 16);   // broadcast b128
#pragma unroll
            for (int p = 0; p < 4; ++p)
#pragma unroll
                for (int o = 0; o < 4; ++o)
                    acc[p][o] = __fmaf_rn(fA[p], w4[o], acc[p][o]);
        }
    }
#pragma unroll
    for (int p = 0; p < 4; ++p) {
        float* op = xd + (size_t)(gy * 128 + gx0 + p) * 256 + ocB;
#pragma unroll
        for (int o = 0; o < 4; ++o) {
            float v = __fadd_rn(acc[p][o], rpn_b[ocB + o]);
            op[o] = v > 0.f ? v : 0.f;
        }
    }
}

// ---------------- heads: 1x1 convs, k=ic sequential f32 FMA (float4 loads) ---
__global__ __launch_bounds__(256, 1) void heads_seq(const float* __restrict__ xd,
                                                    const float* __restrict__ cls_w,
                                                    const float* __restrict__ box_w,
                                                    float* __restrict__ dots) {
    __shared__ float sX[4][260];
    const int tid = threadIdx.x;
    const int pix0 = blockIdx.x * 4;
    for (int idx = tid; idx < 1024; idx += 256)
        sX[idx >> 8][idx & 255] = xd[(size_t)(pix0 + (idx >> 8)) * 256 + (idx & 255)];
    __syncthreads();
    if (tid < 216) {
        const int pl = tid / 54, o = tid % 54;
        const float* wr = (o < 18) ? (cls_w + o * 256) : (box_w + (o - 18) * 256);
        const float4* x4 = (const float4*)&sX[pl][0];
        const float4* w4 = (const float4*)wr;
        float acc = 0.f;
        for (int q = 0; q < 64; ++q) {
            float4 xv = x4[q];
            float4 wv = w4[q];
            acc = __fmaf_rn(xv.x, wv.x, acc);
            acc = __fmaf_rn(xv.y, wv.y, acc);
            acc = __fmaf_rn(xv.z, wv.z, acc);
            acc = __fmaf_rn(xv.w, wv.w, acc);
        }
        dots[(size_t)(pix0 + pl) * 54 + o] = acc;
    }
}

// ---------------- decode: stepwise-F32 softmax + box decode, XLA exp ---------
__global__ __launch_bounds__(256, 1) void decode(const float* __restrict__ dots,
                                                 const float* __restrict__ cls_b,
                                                 const float* __restrict__ box_b,
                                                 float4* __restrict__ boxes,
                                                 u64* __restrict__ keys) {
    const int pix = blockIdx.x * 256 + threadIdx.x;
    if (pix >= 16384) return;
    const float* dt = dots + (size_t)pix * 54;
    float d[54];
#pragma unroll
    for (int i = 0; i < 54; ++i)
        d[i] = __fadd_rn(dt[i], (i < 18 ? cls_b[i] : box_b[i - 18]));
    float m = d[0];
#pragma unroll
    for (int i = 1; i < 18; ++i) m = fmaxf(m, d[i]);
    float e[18];
#pragma unroll
    for (int i = 0; i < 18; ++i) e[i] = exp_xla(__fsub_rn(d[i], m));
    float s = e[0];
#pragma unroll
    for (int i = 1; i < 18; ++i) s = __fadd_rn(s, e[i]);
    const int y = pix >> 7, x = pix & 127;
    const float shx = (float)(x * 32), shy = (float)(y * 32);
    const float AW[9] = {368.f, 736.f, 1472.f, 256.f, 512.f, 1024.f, 176.f, 352.f, 704.f};
    const float AH[9] = {192.f, 384.f, 768.f, 256.f, 512.f, 1024.f, 352.f, 704.f, 1408.f};
#pragma unroll
    for (int a = 0; a < 9; ++a) {
        float score = e[9 + a] / s;
        float wa = AW[a], ha = AH[a];
        float cxa = __fadd_rn(shx, 7.5f), cya = __fadd_rn(shy, 7.5f);
        float dx = d[18 + 4 * a], dyy = d[19 + 4 * a];
        float dw = d[20 + 4 * a], dh = d[21 + 4 * a];
        float cx = __fadd_rn(__fmul_rn(dx, wa), cxa);
        float cy = __fadd_rn(__fmul_rn(dyy, ha), cya);
        float pw = __fmul_rn(wa, exp_xla(dw));
        float ph = __fmul_rn(ha, exp_xla(dh));
        float hx = __fmul_rn(0.5f, pw), hy = __fmul_rn(0.5f, ph);
        float x1 = fminf(fmaxf(__fsub_rn(cx, hx), 0.f), 4095.f);
        float y1 = fminf(fmaxf(__fsub_rn(cy, hy), 0.f), 4095.f);
        float x2 = fminf(fmaxf(__fadd_rn(cx, hx), 0.f), 4095.f);
        float y2 = fminf(fmaxf(__fadd_rn(cy, hy), 0.f), 4095.f);
        float vw = __fadd_rn(__fsub_rn(x2, x1), 1.0f);
        float vh = __fadd_rn(__fsub_rn(y2, y1), 1.0f);
        bool valid = (vw >= 16.0f) && (vh >= 16.0f);
        int i = pix * 9 + a;
        boxes[i] = make_float4(x1, y1, x2, y2);
        u64 k;
        if (valid) {
            u32 b = __float_as_uint(score);
            k = ((u64)(u32)~(b | 0x80000000u) << 32) | (u32)i;
        } else {
            k = (0xFFFFFFFFULL << 32) | (u32)i;
        }
        keys[i] = k;
    }
}

// ---------------- radix select: 8 passes of 8 bits, LDS histograms -----------
__global__ __launch_bounds__(256) void hist8(const u64* __restrict__ keys,
                                             u32* __restrict__ ghist,
                                             const u64* __restrict__ pfx, int pass) {
    __shared__ u32 lh[256];
    lh[threadIdx.x] = 0;
    __syncthreads();
    const u64 pref = *pfx;
    const int shift = 56 - 8 * pass;
    for (int i = blockIdx.x * 256 + threadIdx.x; i < 147456; i += 64 * 256) {
        u64 k = keys[i];
        bool match = (pass == 0) || ((k >> (shift + 8)) == pref);
        if (match) atomicAdd(&lh[(u32)(k >> shift) & 0xFFu], 1u);
    }
    __syncthreads();
    if (lh[threadIdx.x]) atomicAdd(&ghist[threadIdx.x], lh[threadIdx.x]);
}

__global__ __launch_bounds__(256) void scan8(const u32* __restrict__ ghist,
                                             u64* pfx, u32* tgt, int pass) {
    __shared__ u32 h[256];
    __shared__ u32 incl[256];
    const int t = threadIdx.x;
    u32 target = (pass == 0) ? 6000u : *tgt;
    u64 p0 = (pass == 0) ? 0ULL : *pfx;
    h[t] = ghist[t];
    incl[t] = h[t];
    __syncthreads();
    for (int off = 1; off < 256; off <<= 1) {
        u32 v = (t >= off) ? incl[t - off] : 0u;
        __syncthreads();
        incl[t] += v;
        __syncthreads();
    }
    u32 before = incl[t] - h[t];
    if (before < target && target <= incl[t]) {
        *pfx = (p0 << 8) | (u64)t;
        *tgt = target - before;
    }
}

__global__ void compact(const u64* __restrict__ keys, const u64* __restrict__ kstar,
                        u32* count, u64* __restrict__ ckey, u32* __restrict__ cidx) {
    int i = blockIdx.x * 256 + threadIdx.x;
    if (i >= 147456) return;
    u64 k = keys[i];
    if (k <= *kstar) {
        u32 pos = atomicAdd(count, 1u);
        if (pos < 6144) { ckey[pos] = k; cidx[pos] = (u32)(k & 0xFFFFFFFFu); }
    }
}

// ---------------- exact rank (keys unique) + gather sorted top-6000 ----------
__global__ __launch_bounds__(256) void rank_scatter(const u64* __restrict__ ckey,
                                                    const u32* __restrict__ cidx,
                                                    const u32* __restrict__ count,
                                                    const float4* __restrict__ boxes,
                                                    float4* __restrict__ tb,
                                                    float* __restrict__ tsc) {
    __shared__ u64 LK[6144];
    int N = (int)*count; if (N > 6144) N = 6144;
    for (int i = threadIdx.x; i < N; i += 256) LK[i] = ckey[i];
    __syncthreads();
    int e = blockIdx.x * 256 + threadIdx.x;
    if (e >= N) return;
    u64 myK = LK[e];
    u32 myI = cidx[e];
    int rank = 0;
    for (int c = 0; c < N; ++c) rank += (LK[c] < myK);
    if (rank < 6000) {
        tb[rank] = boxes[myI];
        u32 hi = (u32)(myK >> 32);
        tsc[rank] = (hi == 0xFFFFFFFFu) ? -__builtin_inff()
                                        : __uint_as_float(~hi & 0x7FFFFFFFu);
    }
}

// ---------------- alive bitmask init -----------------------------------------
__global__ void alive_init(const float* __restrict__ tsc, u64* __restrict__ alive0) {
    int r = blockIdx.x * 256 + threadIdx.x;
    bool a = false;
    if (r < 6000) a = tsc[r] > -__builtin_inff();
    u64 b = __ballot(a);
    if ((threadIdx.x & 63) == 0) alive0[r >> 6] = b;
}

// ---------------- suppression bitmask: m[j][i] = iou(tb[j],tb[i]) > 0.7 ------
__global__ __launch_bounds__(256) void nms_mask(const float4* __restrict__ tb,
                                                u64* __restrict__ mask) {
    int tid = blockIdx.x * 256 + threadIdx.x;
    if (tid >= 6000 * 94) return;
    int j = tid / 94, w = tid % 94;
    float4 bj = tb[j];
    float arJ = __fmul_rn(__fadd_rn(__fsub_rn(bj.z, bj.x), 1.0f),
                          __fadd_rn(__fsub_rn(bj.w, bj.y), 1.0f));
    u64 m = 0;
    int base = w * 64;
#pragma unroll 4
    for (int b = 0; b < 64; ++b) {
        int i = base + b;
        if (i >= 6000) break;
        float4 bi = tb[i];
        float arI = __fmul_rn(__fadd_rn(__fsub_rn(bi.z, bi.x), 1.0f),
                              __fadd_rn(__fsub_rn(bi.w, bi.y), 1.0f));
        float xx1 = fmaxf(bj.x, bi.x), yy1 = fmaxf(bj.y, bi.y);
        float xx2 = fminf(bj.z, bi.z), yy2 = fminf(bj.w, bi.w);
        float ww = fmaxf(__fadd_rn(__fsub_rn(xx2, xx1), 1.0f), 0.0f);
        float hh = fmaxf(__fadd_rn(__fsub_rn(yy2, yy1), 1.0f), 0.0f);
        float inter = __fmul_rn(ww, hh);
        float uni = __fsub_rn(__fadd_rn(arJ, arI), inter);
        float iou = inter / uni;
        if (iou > 0.7f) m |= (1ULL << b);
    }
    mask[(size_t)j * 96 + w] = m;
}

// ---------------- sequential NMS v2: LDS sliding window + deferred output ----
__global__ __launch_bounds__(64, 1) void nms_seq(const u64* __restrict__ alive0,
                                                 const u64* __restrict__ mask,
                                                 const float4* __restrict__ tb,
                                                 float* __restrict__ out) {
    __shared__ __align__(16) u64 lwin[64 * 96];   // 48 KB: rows [base, base+64)
    __shared__ u32 sel[1000];
    const int lane = threadIdx.x;
    u64 wl = alive0[lane];
    u64 wh = (lane < 30) ? alive0[64 + lane] : 0ULL;
    int base = -1000000;   // force refill on first selection
    int k = 0;
    for (; k < 1000; ++k) {
        // ---- j = first alive (strictly increasing across iterations) ----
        int j;
        {
            u64 blo = __ballot(wl != 0ULL);
            if (blo) {
                int l = __ffsll((long long)blo) - 1;
                u64 w = __shfl(wl, l);
                j = l * 64 + __ffsll((long long)w) - 1;
            } else {
                u64 bhi = __ballot(wh != 0ULL);
                if (!bhi) break;  // exhausted: remaining out rows stay 0
                int l = __ffsll((long long)bhi) - 1;
                u64 w = __shfl(wh, l);
                j = (64 + l) * 64 + __ffsll((long long)w) - 1;
            }
        }
        if (lane == 0) sel[k] = (u32)j;
        // ---- window: LDS hit, or bulk refill [j, j+64) (uniform branch) ----
        int s = j - base;
        if (s < 0 || s >= 64) {
            const char* gsrc = (const char*)mask + (size_t)j * 768 + (size_t)lane * 16;
            char* ldst = (char*)lwin;
#pragma unroll
            for (int i = 0; i < 48; ++i)
                gload_lds16(gsrc + (size_t)i * 1024, ldst + i * 1024);
            base = j;
            s = 0;
            asm volatile("s_waitcnt vmcnt(0)" ::: "memory");
        }
        u64 rl = lwin[(size_t)s * 96 + lane];
        u64 rh = (lane < 30) ? lwin[(size_t)s * 96 + 64 + lane] : 0ULL;
        // ---- apply row j (kills j itself via iou==1) ----
        wl &= ~rl;
        if (lane < 30) wh &= ~rh;
    }
    // ---- bulk gather: rois[k] = (0, tb[sel[k]]) — off the serial path ----
    __syncthreads();
    for (int r = lane; r < k; r += 64) {
        int j = (int)sel[r];
        float4 bj = tb[j];
        out[r * 5 + 1] = bj.x;
        out[r * 5 + 2] = bj.y;
        out[r * 5 + 3] = bj.z;
        out[r * 5 + 4] = bj.w;
    }
}

// ---------------- host ----------------
extern "C" void kernel_launch(void* const* d_in, const int* in_sizes, int n_in,
                              void* d_out, int out_size, void* d_ws, size_t ws_size,
                              hipStream_t stream) {
    const float *feat = nullptr, *rpn_w = nullptr, *rpn_b = nullptr;
    const float *cls_w = nullptr, *cls_b = nullptr, *box_w = nullptr, *box_b = nullptr;
    for (int i = 0; i < n_in; ++i) {
        switch (in_sizes[i]) {
            case 4194304: feat  = (const float*)d_in[i]; break;
            case 589824:  rpn_w = (const float*)d_in[i]; break;
            case 256:     rpn_b = (const float*)d_in[i]; break;
            case 4608:    cls_w = (const float*)d_in[i]; break;
            case 18:      cls_b = (const float*)d_in[i]; break;
            case 9216:    box_w = (const float*)d_in[i]; break;
            case 36:      box_b = (const float*)d_in[i]; break;
            default: break;  // image dims hardcoded (4096)
        }
    }

    char* w = (char*)d_ws;
    u64* pfx       = (u64*)(w + OFF_CTL);
    u32* tgt       = (u32*)(w + OFF_CTL + 8);
    u32* ctlCount  = (u32*)(w + OFF_CTL + 12);
    u32* hist      = (u32*)(w + OFF_HIST);
    float* dots    = (float*)(w + OFF_DOTS);
    float* wcv     = (float*)(w + OFF_WCV);
    float* xd      = (float*)(w + OFF_XD);
    float4* boxes  = (float4*)(w + OFF_BOX);
    u64* keys      = (u64*)(w + OFF_KEYS);
    u64* ckey      = (u64*)(w + OFF_CKEY);
    u32* cidx      = (u32*)(w + OFF_CIDX);
    float4* tb     = (float4*)(w + OFF_TB);
    float* tsc     = (float*)(w + OFF_TSC);
    u64* alive0    = (u64*)(w + OFF_ALIVE);
    u64* mask      = (u64*)(w + OFF_MASK);
    float* featP   = (float*)(w + OFF_FPAD);

    hipMemsetAsync(d_ws, 0, OFF_HIST + 8 * 256 * 4, stream);  // ctl + 8 hists
    hipMemsetAsync(d_out, 0, (size_t)out_size * sizeof(float), stream);

    prep_wcv<<<2304, 256, 0, stream>>>(rpn_w, wcv);
    prep_pad<<<17160, 256, 0, stream>>>(feat, featP);
    conv3x3<<<1024, 256, 0, stream>>>(featP, wcv, rpn_b, xd);
    heads_seq<<<4096, 256, 0, stream>>>(xd, cls_w, box_w, dots);
    decode<<<64, 256, 0, stream>>>(dots, cls_b, box_b, boxes, keys);
    for (int p = 0; p < 8; ++p) {
        hist8<<<64, 256, 0, stream>>>(keys, hist + p * 256, pfx, p);
        scan8<<<1, 256, 0, stream>>>(hist + p * 256, pfx, tgt, p);
    }
    compact<<<576, 256, 0, stream>>>(keys, pfx, ctlCount, ckey, cidx);
    rank_scatter<<<24, 256, 0, stream>>>(ckey, cidx, ctlCount, boxes, tb, tsc);
    alive_init<<<24, 256, 0, stream>>>(tsc, alive0);
    nms_mask<<<2204, 256, 0, stream>>>(tb, mask);
    nms_seq<<<1, 64, 0, stream>>>(alive0, mask, tb, (float*)d_out);
}

// Round 3
// 1059.484 us; speedup vs baseline: 1.1814x; 1.1814x over previous
//
#include <hip/hip_runtime.h>
#include <stdint.h>
#include <math.h>

typedef unsigned long long u64;
typedef unsigned int u32;
typedef float float4a __attribute__((ext_vector_type(4), aligned(4)));

// ---------------- workspace layout (bytes) ----------------
static const size_t OFF_CTL   = 0;          // [0]=u64 prefix/kstar, [8]=u32 target, [12]=u32 count
static const size_t OFF_HIST  = 1024;       // 8 passes * 256 * 4 = 8 KB
static const size_t OFF_DOTS  = 1049600;    // 16384*54*4
static const size_t OFF_WCV   = 4588544;    // 589824*4  [tap][ic][oc]
static const size_t OFF_XD    = 6947840;    // 16384*256*4 (conv out f32, HWC)
static const size_t OFF_BOX   = 23725056;   // 147456*16 (float4)
static const size_t OFF_KEYS  = 26084352;   // 147456*8
static const size_t OFF_CKEY  = 27264000;   // 6144*8
static const size_t OFF_CIDX  = 27313152;   // 6144*4
static const size_t OFF_TB    = 27337728;   // 6000*16
static const size_t OFF_TSC   = 27433728;   // 6000*4
static const size_t OFF_ALIVE = 27458048;   // 128*8
static const size_t OFF_MASK  = 27459072;   // 6000*96*8 = 4608000
static const size_t OFF_FPAD  = 32067584;   // 256*130*132*4 = 17571840  end ~49.6 MB

// XLA-CPU / Eigen / Cephes f32 exp (FMA form) — bit-matches the np reference.
__device__ __forceinline__ float exp_xla(float x) {
    float m = floorf(__fmaf_rn(x, 1.44269504088896341f, 0.5f));
    float r = __fmaf_rn(m, -0.693359375f, x);
    r = __fmaf_rn(m, 2.12194440e-4f, r);
    float r2 = r * r;
    float p = 1.9875691500e-4f;
    p = __fmaf_rn(p, r, 1.3981999507e-3f);
    p = __fmaf_rn(p, r, 8.3334519073e-3f);
    p = __fmaf_rn(p, r, 4.1665795894e-2f);
    p = __fmaf_rn(p, r, 1.6666665459e-1f);
    p = __fmaf_rn(p, r, 5.0000001201e-1f);
    p = __fmaf_rn(p, r2, r);
    p = __fadd_rn(p, 1.0f);
    int mi = (int)m;
    return p * __int_as_float((mi + 127) << 23);
}

// async global->LDS, 16B per lane, wave-uniform LDS base + lane*16
__device__ __forceinline__ void gload_lds16(const void* g, void* l) {
    __builtin_amdgcn_global_load_lds(
        (const __attribute__((address_space(1))) void*)g,
        (__attribute__((address_space(3))) void*)l, 16, 0, 0);
}

// ---------------- weight prep: rpn_w [oc][ic][tap] -> f32 [tap][ic][oc] ------
__global__ void prep_wcv(const float* __restrict__ rpn_w, float* __restrict__ wcv) {
    int t = blockIdx.x * 256 + threadIdx.x;
    if (t >= 589824) return;
    int tap = t / 65536, rem = t % 65536, ic = rem / 256, oc = rem % 256;
    wcv[t] = rpn_w[oc * 2304 + ic * 9 + tap];
}

// ---------------- feature pad: featP[ic][130][132], +1 halo of literal zeros -
__global__ void prep_pad(const float* __restrict__ feat, float* __restrict__ featP) {
    int t = blockIdx.x * 256 + threadIdx.x;
    if (t >= 256 * 130 * 132) return;
    int ic = t / 17160, rem = t % 17160, y = rem / 132, x = rem % 132;
    int sy = y - 1, sx = x - 1;
    float v = 0.f;
    if (sy >= 0 && sy < 128 && sx >= 0 && sx < 128)
        v = feat[ic * 16384 + sy * 128 + sx];
    featP[t] = v;
}

// ---------------- conv3x3 v3: v1 tiling (8px x 4oc) + ic-unroll-4 prefetch ---
// R2 post-mortem: VALU-issue cycles are conserved across tilings (0.388*477 ==
// 0.28*690); the limiter is the per-iteration dependent L2 feature load
// (~200-300cy) covered by only ~64cy FMA (VGPR=48 -> 1-deep pipeline).
// Fix: manual ic-unroll x4 — all 8 feature loads + 4 weight loads issued
// before the 128-FMA burst, giving the scheduler a 4-deep prefetch window.
// Per-output chain UNCHANGED (tap-major, ic 0..255 ascending, one f32 acc,
// __fmaf_rn) -> bit-exact.
#define FMA_GRP(FA, FB, W4)                                            \
    _Pragma("unroll")                                                  \
    for (int p = 0; p < 4; ++p)                                        \
        _Pragma("unroll")                                              \
        for (int o = 0; o < 4; ++o)                                    \
            acc[p][o] = __fmaf_rn(FA[p], W4[o], acc[p][o]);            \
    _Pragma("unroll")                                                  \
    for (int p = 0; p < 4; ++p)                                        \
        _Pragma("unroll")                                              \
        for (int o = 0; o < 4; ++o)                                    \
            acc[4 + p][o] = __fmaf_rn(FB[p], W4[o], acc[4 + p][o]);

__global__ __launch_bounds__(256, 2) void conv3x3(const float* __restrict__ featP,
                                                  const float* __restrict__ wcv,
                                                  const float* __restrict__ rpn_b,
                                                  float* __restrict__ xd) {
    __shared__ float sW[8192];                 // [ic][32 oc] for current tap
    const int band = blockIdx.x & 7;           // tile row (XCD-pinned)
    const int slot = blockIdx.x >> 3;          // 0..63
    const int tx = slot & 7, ocb = slot >> 3;  // tile col, oc-block(32)
    const int oc0 = ocb * 32;
    const int tid = threadIdx.x;
    const int ocg = tid >> 5;                  // 0..7 -> 4 oc each
    const int oct = tid & 31;
    const int py = oct >> 1, px0 = (oct & 1) * 8;
    const int gy = band * 16 + py, gx0 = tx * 16 + px0;
    const int ocB = oc0 + ocg * 4;
    float acc[8][4];
#pragma unroll
    for (int p = 0; p < 8; ++p)
#pragma unroll
        for (int o = 0; o < 4; ++o) acc[p][o] = 0.f;
#pragma unroll
    for (int tap = 0; tap < 9; ++tap) {        // k-major: tap (ky,kx)
        __syncthreads();
        for (int idx = tid; idx < 8192; idx += 256)
            sW[idx] = wcv[tap * 65536 + (idx >> 5) * 256 + oc0 + (idx & 31)];
        __syncthreads();
        const float* fp = featP + (size_t)(gy + tap / 3) * 132 + (gx0 + tap % 3);
        const float* wl = sW + ocg * 4;
        for (int ic = 0; ic < 256; ic += 4) {  // k-minor: ic ascending, x4
            const float* f0 = fp + (size_t)(ic + 0) * 17160;
            const float* f1 = fp + (size_t)(ic + 1) * 17160;
            const float* f2 = fp + (size_t)(ic + 2) * 17160;
            const float* f3 = fp + (size_t)(ic + 3) * 17160;
            float4a fA0 = *(const float4a*)(f0);
            float4a fB0 = *(const float4a*)(f0 + 4);
            float4a fA1 = *(const float4a*)(f1);
            float4a fB1 = *(const float4a*)(f1 + 4);
            float4a fA2 = *(const float4a*)(f2);
            float4a fB2 = *(const float4a*)(f2 + 4);
            float4a fA3 = *(const float4a*)(f3);
            float4a fB3 = *(const float4a*)(f3 + 4);
            float4a w40 = *(const float4a*)(wl + (ic + 0) * 32);
            float4a w41 = *(const float4a*)(wl + (ic + 1) * 32);
            float4a w42 = *(const float4a*)(wl + (ic + 2) * 32);
            float4a w43 = *(const float4a*)(wl + (ic + 3) * 32);
            FMA_GRP(fA0, fB0, w40)
            FMA_GRP(fA1, fB1, w41)
            FMA_GRP(fA2, fB2, w42)
            FMA_GRP(fA3, fB3, w43)
        }
    }
#pragma unroll
    for (int p = 0; p < 8; ++p) {
        float* op = xd + (size_t)(gy * 128 + gx0 + p) * 256 + ocB;
#pragma unroll
        for (int o = 0; o < 4; ++o) {
            float v = __fadd_rn(acc[p][o], rpn_b[ocB + o]);
            op[o] = v > 0.f ? v : 0.f;
        }
    }
}

// ---------------- heads: 1x1 convs, k=ic sequential f32 FMA (float4 loads) ---
__global__ __launch_bounds__(256, 1) void heads_seq(const float* __restrict__ xd,
                                                    const float* __restrict__ cls_w,
                                                    const float* __restrict__ box_w,
                                                    float* __restrict__ dots) {
    __shared__ float sX[4][260];
    const int tid = threadIdx.x;
    const int pix0 = blockIdx.x * 4;
    for (int idx = tid; idx < 1024; idx += 256)
        sX[idx >> 8][idx & 255] = xd[(size_t)(pix0 + (idx >> 8)) * 256 + (idx & 255)];
    __syncthreads();
    if (tid < 216) {
        const int pl = tid / 54, o = tid % 54;
        const float* wr = (o < 18) ? (cls_w + o * 256) : (box_w + (o - 18) * 256);
        const float4* x4 = (const float4*)&sX[pl][0];
        const float4* w4 = (const float4*)wr;
        float acc = 0.f;
        for (int q = 0; q < 64; ++q) {
            float4 xv = x4[q];
            float4 wv = w4[q];
            acc = __fmaf_rn(xv.x, wv.x, acc);
            acc = __fmaf_rn(xv.y, wv.y, acc);
            acc = __fmaf_rn(xv.z, wv.z, acc);
            acc = __fmaf_rn(xv.w, wv.w, acc);
        }
        dots[(size_t)(pix0 + pl) * 54 + o] = acc;
    }
}

// ---------------- decode: stepwise-F32 softmax + box decode, XLA exp ---------
__global__ __launch_bounds__(256, 1) void decode(const float* __restrict__ dots,
                                                 const float* __restrict__ cls_b,
                                                 const float* __restrict__ box_b,
                                                 float4* __restrict__ boxes,
                                                 u64* __restrict__ keys) {
    const int pix = blockIdx.x * 256 + threadIdx.x;
    if (pix >= 16384) return;
    const float* dt = dots + (size_t)pix * 54;
    float d[54];
#pragma unroll
    for (int i = 0; i < 54; ++i)
        d[i] = __fadd_rn(dt[i], (i < 18 ? cls_b[i] : box_b[i - 18]));
    float m = d[0];
#pragma unroll
    for (int i = 1; i < 18; ++i) m = fmaxf(m, d[i]);
    float e[18];
#pragma unroll
    for (int i = 0; i < 18; ++i) e[i] = exp_xla(__fsub_rn(d[i], m));
    float s = e[0];
#pragma unroll
    for (int i = 1; i < 18; ++i) s = __fadd_rn(s, e[i]);
    const int y = pix >> 7, x = pix & 127;
    const float shx = (float)(x * 32), shy = (float)(y * 32);
    const float AW[9] = {368.f, 736.f, 1472.f, 256.f, 512.f, 1024.f, 176.f, 352.f, 704.f};
    const float AH[9] = {192.f, 384.f, 768.f, 256.f, 512.f, 1024.f, 352.f, 704.f, 1408.f};
#pragma unroll
    for (int a = 0; a < 9; ++a) {
        float score = e[9 + a] / s;
        float wa = AW[a], ha = AH[a];
        float cxa = __fadd_rn(shx, 7.5f), cya = __fadd_rn(shy, 7.5f);
        float dx = d[18 + 4 * a], dyy = d[19 + 4 * a];
        float dw = d[20 + 4 * a], dh = d[21 + 4 * a];
        float cx = __fadd_rn(__fmul_rn(dx, wa), cxa);
        float cy = __fadd_rn(__fmul_rn(dyy, ha), cya);
        float pw = __fmul_rn(wa, exp_xla(dw));
        float ph = __fmul_rn(ha, exp_xla(dh));
        float hx = __fmul_rn(0.5f, pw), hy = __fmul_rn(0.5f, ph);
        float x1 = fminf(fmaxf(__fsub_rn(cx, hx), 0.f), 4095.f);
        float y1 = fminf(fmaxf(__fsub_rn(cy, hy), 0.f), 4095.f);
        float x2 = fminf(fmaxf(__fadd_rn(cx, hx), 0.f), 4095.f);
        float y2 = fminf(fmaxf(__fadd_rn(cy, hy), 0.f), 4095.f);
        float vw = __fadd_rn(__fsub_rn(x2, x1), 1.0f);
        float vh = __fadd_rn(__fsub_rn(y2, y1), 1.0f);
        bool valid = (vw >= 16.0f) && (vh >= 16.0f);
        int i = pix * 9 + a;
        boxes[i] = make_float4(x1, y1, x2, y2);
        u64 k;
        if (valid) {
            u32 b = __float_as_uint(score);
            k = ((u64)(u32)~(b | 0x80000000u) << 32) | (u32)i;
        } else {
            k = (0xFFFFFFFFULL << 32) | (u32)i;
        }
        keys[i] = k;
    }
}

// ---------------- radix select: 8 passes of 8 bits, LDS histograms -----------
__global__ __launch_bounds__(256) void hist8(const u64* __restrict__ keys,
                                             u32* __restrict__ ghist,
                                             const u64* __restrict__ pfx, int pass) {
    __shared__ u32 lh[256];
    lh[threadIdx.x] = 0;
    __syncthreads();
    const u64 pref = *pfx;
    const int shift = 56 - 8 * pass;
    for (int i = blockIdx.x * 256 + threadIdx.x; i < 147456; i += 64 * 256) {
        u64 k = keys[i];
        bool match = (pass == 0) || ((k >> (shift + 8)) == pref);
        if (match) atomicAdd(&lh[(u32)(k >> shift) & 0xFFu], 1u);
    }
    __syncthreads();
    if (lh[threadIdx.x]) atomicAdd(&ghist[threadIdx.x], lh[threadIdx.x]);
}

__global__ __launch_bounds__(256) void scan8(const u32* __restrict__ ghist,
                                             u64* pfx, u32* tgt, int pass) {
    __shared__ u32 h[256];
    __shared__ u32 incl[256];
    const int t = threadIdx.x;
    u32 target = (pass == 0) ? 6000u : *tgt;
    u64 p0 = (pass == 0) ? 0ULL : *pfx;
    h[t] = ghist[t];
    incl[t] = h[t];
    __syncthreads();
    for (int off = 1; off < 256; off <<= 1) {
        u32 v = (t >= off) ? incl[t - off] : 0u;
        __syncthreads();
        incl[t] += v;
        __syncthreads();
    }
    u32 before = incl[t] - h[t];
    if (before < target && target <= incl[t]) {
        *pfx = (p0 << 8) | (u64)t;
        *tgt = target - before;
    }
}

__global__ void compact(const u64* __restrict__ keys, const u64* __restrict__ kstar,
                        u32* count, u64* __restrict__ ckey, u32* __restrict__ cidx) {
    int i = blockIdx.x * 256 + threadIdx.x;
    if (i >= 147456) return;
    u64 k = keys[i];
    if (k <= *kstar) {
        u32 pos = atomicAdd(count, 1u);
        if (pos < 6144) { ckey[pos] = k; cidx[pos] = (u32)(k & 0xFFFFFFFFu); }
    }
}

// ---------------- exact rank (keys unique) + gather sorted top-6000 ----------
__global__ __launch_bounds__(256) void rank_scatter(const u64* __restrict__ ckey,
                                                    const u32* __restrict__ cidx,
                                                    const u32* __restrict__ count,
                                                    const float4* __restrict__ boxes,
                                                    float4* __restrict__ tb,
                                                    float* __restrict__ tsc) {
    __shared__ u64 LK[6144];
    int N = (int)*count; if (N > 6144) N = 6144;
    for (int i = threadIdx.x; i < N; i += 256) LK[i] = ckey[i];
    __syncthreads();
    int e = blockIdx.x * 256 + threadIdx.x;
    if (e >= N) return;
    u64 myK = LK[e];
    u32 myI = cidx[e];
    int rank = 0;
    for (int c = 0; c < N; ++c) rank += (LK[c] < myK);
    if (rank < 6000) {
        tb[rank] = boxes[myI];
        u32 hi = (u32)(myK >> 32);
        tsc[rank] = (hi == 0xFFFFFFFFu) ? -__builtin_inff()
                                        : __uint_as_float(~hi & 0x7FFFFFFFu);
    }
}

// ---------------- alive bitmask init -----------------------------------------
__global__ void alive_init(const float* __restrict__ tsc, u64* __restrict__ alive0) {
    int r = blockIdx.x * 256 + threadIdx.x;
    bool a = false;
    if (r < 6000) a = tsc[r] > -__builtin_inff();
    u64 b = __ballot(a);
    if ((threadIdx.x & 63) == 0) alive0[r >> 6] = b;
}

// ---------------- suppression bitmask: m[j][i] = iou(tb[j],tb[i]) > 0.7 ------
__global__ __launch_bounds__(256) void nms_mask(const float4* __restrict__ tb,
                                                u64* __restrict__ mask) {
    int tid = blockIdx.x * 256 + threadIdx.x;
    if (tid >= 6000 * 94) return;
    int j = tid / 94, w = tid % 94;
    float4 bj = tb[j];
    float arJ = __fmul_rn(__fadd_rn(__fsub_rn(bj.z, bj.x), 1.0f),
                          __fadd_rn(__fsub_rn(bj.w, bj.y), 1.0f));
    u64 m = 0;
    int base = w * 64;
#pragma unroll 4
    for (int b = 0; b < 64; ++b) {
        int i = base + b;
        if (i >= 6000) break;
        float4 bi = tb[i];
        float arI = __fmul_rn(__fadd_rn(__fsub_rn(bi.z, bi.x), 1.0f),
                              __fadd_rn(__fsub_rn(bi.w, bi.y), 1.0f));
        float xx1 = fmaxf(bj.x, bi.x), yy1 = fmaxf(bj.y, bi.y);
        float xx2 = fminf(bj.z, bi.z), yy2 = fminf(bj.w, bi.w);
        float ww = fmaxf(__fadd_rn(__fsub_rn(xx2, xx1), 1.0f), 0.0f);
        float hh = fmaxf(__fadd_rn(__fsub_rn(yy2, yy1), 1.0f), 0.0f);
        float inter = __fmul_rn(ww, hh);
        float uni = __fsub_rn(__fadd_rn(arJ, arI), inter);
        float iou = inter / uni;
        if (iou > 0.7f) m |= (1ULL << b);
    }
    mask[(size_t)j * 96 + w] = m;
}

// ---------------- sequential NMS v2: LDS sliding window + deferred output ----
__global__ __launch_bounds__(64, 1) void nms_seq(const u64* __restrict__ alive0,
                                                 const u64* __restrict__ mask,
                                                 const float4* __restrict__ tb,
                                                 float* __restrict__ out) {
    __shared__ __align__(16) u64 lwin[64 * 96];   // 48 KB: rows [base, base+64)
    __shared__ u32 sel[1000];
    const int lane = threadIdx.x;
    u64 wl = alive0[lane];
    u64 wh = (lane < 30) ? alive0[64 + lane] : 0ULL;
    int base = -1000000;   // force refill on first selection
    int k = 0;
    for (; k < 1000; ++k) {
        // ---- j = first alive (strictly increasing across iterations) ----
        int j;
        {
            u64 blo = __ballot(wl != 0ULL);
            if (blo) {
                int l = __ffsll((long long)blo) - 1;
                u64 w = __shfl(wl, l);
                j = l * 64 + __ffsll((long long)w) - 1;
            } else {
                u64 bhi = __ballot(wh != 0ULL);
                if (!bhi) break;  // exhausted: remaining out rows stay 0
                int l = __ffsll((long long)bhi) - 1;
                u64 w = __shfl(wh, l);
                j = (64 + l) * 64 + __ffsll((long long)w) - 1;
            }
        }
        if (lane == 0) sel[k] = (u32)j;
        // ---- window: LDS hit, or bulk refill [j, j+64) (uniform branch) ----
        int s = j - base;
        if (s < 0 || s >= 64) {
            const char* gsrc = (const char*)mask + (size_t)j * 768 + (size_t)lane * 16;
            char* ldst = (char*)lwin;
#pragma unroll
            for (int i = 0; i < 48; ++i)
                gload_lds16(gsrc + (size_t)i * 1024, ldst + i * 1024);
            base = j;
            s = 0;
            asm volatile("s_waitcnt vmcnt(0)" ::: "memory");
        }
        u64 rl = lwin[(size_t)s * 96 + lane];
        u64 rh = (lane < 30) ? lwin[(size_t)s * 96 + 64 + lane] : 0ULL;
        // ---- apply row j (kills j itself via iou==1) ----
        wl &= ~rl;
        if (lane < 30) wh &= ~rh;
    }
    // ---- bulk gather: rois[k] = (0, tb[sel[k]]) — off the serial path ----
    __syncthreads();
    for (int r = lane; r < k; r += 64) {
        int j = (int)sel[r];
        float4 bj = tb[j];
        out[r * 5 + 1] = bj.x;
        out[r * 5 + 2] = bj.y;
        out[r * 5 + 3] = bj.z;
        out[r * 5 + 4] = bj.w;
    }
}

// ---------------- host ----------------
extern "C" void kernel_launch(void* const* d_in, const int* in_sizes, int n_in,
                              void* d_out, int out_size, void* d_ws, size_t ws_size,
                              hipStream_t stream) {
    const float *feat = nullptr, *rpn_w = nullptr, *rpn_b = nullptr;
    const float *cls_w = nullptr, *cls_b = nullptr, *box_w = nullptr, *box_b = nullptr;
    for (int i = 0; i < n_in; ++i) {
        switch (in_sizes[i]) {
            case 4194304: feat  = (const float*)d_in[i]; break;
            case 589824:  rpn_w = (const float*)d_in[i]; break;
            case 256:     rpn_b = (const float*)d_in[i]; break;
            case 4608:    cls_w = (const float*)d_in[i]; break;
            case 18:      cls_b = (const float*)d_in[i]; break;
            case 9216:    box_w = (const float*)d_in[i]; break;
            case 36:      box_b = (const float*)d_in[i]; break;
            default: break;  // image dims hardcoded (4096)
        }
    }

    char* w = (char*)d_ws;
    u64* pfx       = (u64*)(w + OFF_CTL);
    u32* tgt       = (u32*)(w + OFF_CTL + 8);
    u32* ctlCount  = (u32*)(w + OFF_CTL + 12);
    u32* hist      = (u32*)(w + OFF_HIST);
    float* dots    = (float*)(w + OFF_DOTS);
    float* wcv     = (float*)(w + OFF_WCV);
    float* xd      = (float*)(w + OFF_XD);
    float4* boxes  = (float4*)(w + OFF_BOX);
    u64* keys      = (u64*)(w + OFF_KEYS);
    u64* ckey      = (u64*)(w + OFF_CKEY);
    u32* cidx      = (u32*)(w + OFF_CIDX);
    float4* tb     = (float4*)(w + OFF_TB);
    float* tsc     = (float*)(w + OFF_TSC);
    u64* alive0    = (u64*)(w + OFF_ALIVE);
    u64* mask      = (u64*)(w + OFF_MASK);
    float* featP   = (float*)(w + OFF_FPAD);

    hipMemsetAsync(d_ws, 0, OFF_HIST + 8 * 256 * 4, stream);  // ctl + 8 hists
    hipMemsetAsync(d_out, 0, (size_t)out_size * sizeof(float), stream);

    prep_wcv<<<2304, 256, 0, stream>>>(rpn_w, wcv);
    prep_pad<<<17160, 256, 0, stream>>>(feat, featP);
    conv3x3<<<512, 256, 0, stream>>>(featP, wcv, rpn_b, xd);
    heads_seq<<<4096, 256, 0, stream>>>(xd, cls_w, box_w, dots);
    decode<<<64, 256, 0, stream>>>(dots, cls_b, box_b, boxes, keys);
    for (int p = 0; p < 8; ++p) {
        hist8<<<64, 256, 0, stream>>>(keys, hist + p * 256, pfx, p);
        scan8<<<1, 256, 0, stream>>>(hist + p * 256, pfx, tgt, p);
    }
    compact<<<576, 256, 0, stream>>>(keys, pfx, ctlCount, ckey, cidx);
    rank_scatter<<<24, 256, 0, stream>>>(ckey, cidx, ctlCount, boxes, tb, tsc);
    alive_init<<<24, 256, 0, stream>>>(tsc, alive0);
    nms_mask<<<2204, 256, 0, stream>>>(tb, mask);
    nms_seq<<<1, 64, 0, stream>>>(alive0, mask, tb, (float*)d_out);
}

// Round 4
// 936.372 us; speedup vs baseline: 1.3367x; 1.1315x over previous
//
#include <hip/hip_runtime.h>
#include <stdint.h>
#include <math.h>

typedef unsigned long long u64;
typedef unsigned int u32;
typedef float float4a __attribute__((ext_vector_type(4), aligned(4)));

// ---------------- workspace layout (bytes) ----------------
static const size_t OFF_CTL   = 0;          // [0]=u64 prefix/kstar, [8]=u32 target, [12]=u32 count
static const size_t OFF_HIST  = 1024;       // 8 passes * 256 * 4 = 8 KB
static const size_t OFF_DOTS  = 1049600;    // 16384*54*4
static const size_t OFF_WCV   = 4588544;    // 589824*4  [tap][ic][oc]
static const size_t OFF_XD    = 6947840;    // 16384*256*4 (conv out f32, HWC)
static const size_t OFF_BOX   = 23725056;   // 147456*16 (float4)
static const size_t OFF_KEYS  = 26084352;   // 147456*8
static const size_t OFF_CKEY  = 27264000;   // 6144*8
static const size_t OFF_CIDX  = 27313152;   // 6144*4
static const size_t OFF_TB    = 27337728;   // 6000*16
static const size_t OFF_TSC   = 27433728;   // 6000*4
static const size_t OFF_ALIVE = 27458048;   // 128*8
static const size_t OFF_MASK  = 27459072;   // 6000*96*8 = 4608000
static const size_t OFF_FPAD  = 32067584;   // 256*130*132*4 = 17571840  end ~49.6 MB

// XLA-CPU / Eigen / Cephes f32 exp (FMA form) — bit-matches the np reference.
__device__ __forceinline__ float exp_xla(float x) {
    float m = floorf(__fmaf_rn(x, 1.44269504088896341f, 0.5f));
    float r = __fmaf_rn(m, -0.693359375f, x);
    r = __fmaf_rn(m, 2.12194440e-4f, r);
    float r2 = r * r;
    float p = 1.9875691500e-4f;
    p = __fmaf_rn(p, r, 1.3981999507e-3f);
    p = __fmaf_rn(p, r, 8.3334519073e-3f);
    p = __fmaf_rn(p, r, 4.1665795894e-2f);
    p = __fmaf_rn(p, r, 1.6666665459e-1f);
    p = __fmaf_rn(p, r, 5.0000001201e-1f);
    p = __fmaf_rn(p, r2, r);
    p = __fadd_rn(p, 1.0f);
    int mi = (int)m;
    return p * __int_as_float((mi + 127) << 23);
}

// async global->LDS, 16B per lane, wave-uniform LDS base + lane*16
__device__ __forceinline__ void gload_lds16(const void* g, void* l) {
    __builtin_amdgcn_global_load_lds(
        (const __attribute__((address_space(1))) void*)g,
        (__attribute__((address_space(3))) void*)l, 16, 0, 0);
}

// ---------------- weight prep: rpn_w [oc][ic][tap] -> f32 [tap][ic][oc] ------
__global__ void prep_wcv(const float* __restrict__ rpn_w, float* __restrict__ wcv) {
    int t = blockIdx.x * 256 + threadIdx.x;
    if (t >= 589824) return;
    int tap = t / 65536, rem = t % 65536, ic = rem / 256, oc = rem % 256;
    wcv[t] = rpn_w[oc * 2304 + ic * 9 + tap];
}

// ---------------- feature pad: featP[ic][130][132], +1 halo of literal zeros -
__global__ void prep_pad(const float* __restrict__ feat, float* __restrict__ featP) {
    int t = blockIdx.x * 256 + threadIdx.x;
    if (t >= 256 * 130 * 132) return;
    int ic = t / 17160, rem = t % 17160, y = rem / 132, x = rem % 132;
    int sy = y - 1, sx = x - 1;
    float v = 0.f;
    if (sy >= 0 && sy < 128 && sx >= 0 && sx < 128)
        v = feat[ic * 16384 + sy * 128 + sx];
    featP[t] = v;
}

// ---------------- conv3x3 v4: 4px x 8oc per thread — halve vmem per FMA ------
// R3 post-mortem: VALU cycles conserved across tilings; prefetch depth and
// occupancy both neutral => vector-memory-throughput-bound. v1's ocg=tid>>5
// made both wave halves load the SAME 8 px (2 dwordx4/iter, 50% duplicate
// lanes; 8x feature redundancy per block). v4: wave = ONE oc-group of 8 oc
// covering all 256 px -> 1 global dwordx4 + 2 LDS broadcast b128 + 32 FMA
// per iter. Global-load instruction count halves; feature redundancy 8x->4x.
// Per-output chain UNCHANGED (tap-major, ic 0..255 ascending, one f32 acc,
// __fmaf_rn) -> bit-exact. Same grid (512), same sW layout (32 KB).
__global__ __launch_bounds__(256, 2) void conv3x3(const float* __restrict__ featP,
                                                  const float* __restrict__ wcv,
                                                  const float* __restrict__ rpn_b,
                                                  float* __restrict__ xd) {
    __shared__ float sW[8192];                 // [ic][32 oc] for current tap
    const int band = blockIdx.x & 7;           // tile row (XCD-pinned)
    const int slot = blockIdx.x >> 3;          // 0..63
    const int tx = slot & 7, ocb = slot >> 3;  // tile col, oc-block(32)
    const int oc0 = ocb * 32;
    const int tid = threadIdx.x;
    const int wid = tid >> 6;                  // wave 0..3 -> 8 oc each
    const int lane = tid & 63;
    const int py = lane >> 2, px0 = (lane & 3) * 4;   // wave covers 16x16 px
    const int gy = band * 16 + py, gx0 = tx * 16 + px0;
    const int ocB = oc0 + wid * 8;
    float acc[4][8];
#pragma unroll
    for (int p = 0; p < 4; ++p)
#pragma unroll
        for (int o = 0; o < 8; ++o) acc[p][o] = 0.f;
#pragma unroll
    for (int tap = 0; tap < 9; ++tap) {        // k-major: tap (ky,kx)
        __syncthreads();
        for (int idx = tid; idx < 8192; idx += 256)
            sW[idx] = wcv[tap * 65536 + (idx >> 5) * 256 + oc0 + (idx & 31)];
        __syncthreads();
        const float* fp = featP + (size_t)(gy + tap / 3) * 132 + (gx0 + tap % 3);
        const float* wl = sW + wid * 8;        // wave-uniform -> LDS broadcast
#pragma unroll 4
        for (int ic = 0; ic < 256; ++ic) {     // k-minor: ic ascending
            float4a fA = *(const float4a*)(fp + (size_t)ic * 17160);
            float4a w0 = *(const float4a*)(wl + ic * 32);
            float4a w1 = *(const float4a*)(wl + ic * 32 + 4);
#pragma unroll
            for (int p = 0; p < 4; ++p) {
#pragma unroll
                for (int o = 0; o < 4; ++o)
                    acc[p][o] = __fmaf_rn(fA[p], w0[o], acc[p][o]);
#pragma unroll
                for (int o = 0; o < 4; ++o)
                    acc[p][4 + o] = __fmaf_rn(fA[p], w1[o], acc[p][4 + o]);
            }
        }
    }
#pragma unroll
    for (int p = 0; p < 4; ++p) {
        float* op = xd + (size_t)(gy * 128 + gx0 + p) * 256 + ocB;
#pragma unroll
        for (int o = 0; o < 8; ++o) {
            float v = __fadd_rn(acc[p][o], rpn_b[ocB + o]);
            op[o] = v > 0.f ? v : 0.f;
        }
    }
}

// ---------------- heads: 1x1 convs, k=ic sequential f32 FMA (float4 loads) ---
__global__ __launch_bounds__(256, 1) void heads_seq(const float* __restrict__ xd,
                                                    const float* __restrict__ cls_w,
                                                    const float* __restrict__ box_w,
                                                    float* __restrict__ dots) {
    __shared__ float sX[4][260];
    const int tid = threadIdx.x;
    const int pix0 = blockIdx.x * 4;
    for (int idx = tid; idx < 1024; idx += 256)
        sX[idx >> 8][idx & 255] = xd[(size_t)(pix0 + (idx >> 8)) * 256 + (idx & 255)];
    __syncthreads();
    if (tid < 216) {
        const int pl = tid / 54, o = tid % 54;
        const float* wr = (o < 18) ? (cls_w + o * 256) : (box_w + (o - 18) * 256);
        const float4* x4 = (const float4*)&sX[pl][0];
        const float4* w4 = (const float4*)wr;
        float acc = 0.f;
        for (int q = 0; q < 64; ++q) {
            float4 xv = x4[q];
            float4 wv = w4[q];
            acc = __fmaf_rn(xv.x, wv.x, acc);
            acc = __fmaf_rn(xv.y, wv.y, acc);
            acc = __fmaf_rn(xv.z, wv.z, acc);
            acc = __fmaf_rn(xv.w, wv.w, acc);
        }
        dots[(size_t)(pix0 + pl) * 54 + o] = acc;
    }
}

// ---------------- decode: stepwise-F32 softmax + box decode, XLA exp ---------
__global__ __launch_bounds__(256, 1) void decode(const float* __restrict__ dots,
                                                 const float* __restrict__ cls_b,
                                                 const float* __restrict__ box_b,
                                                 float4* __restrict__ boxes,
                                                 u64* __restrict__ keys) {
    const int pix = blockIdx.x * 256 + threadIdx.x;
    if (pix >= 16384) return;
    const float* dt = dots + (size_t)pix * 54;
    float d[54];
#pragma unroll
    for (int i = 0; i < 54; ++i)
        d[i] = __fadd_rn(dt[i], (i < 18 ? cls_b[i] : box_b[i - 18]));
    float m = d[0];
#pragma unroll
    for (int i = 1; i < 18; ++i) m = fmaxf(m, d[i]);
    float e[18];
#pragma unroll
    for (int i = 0; i < 18; ++i) e[i] = exp_xla(__fsub_rn(d[i], m));
    float s = e[0];
#pragma unroll
    for (int i = 1; i < 18; ++i) s = __fadd_rn(s, e[i]);
    const int y = pix >> 7, x = pix & 127;
    const float shx = (float)(x * 32), shy = (float)(y * 32);
    const float AW[9] = {368.f, 736.f, 1472.f, 256.f, 512.f, 1024.f, 176.f, 352.f, 704.f};
    const float AH[9] = {192.f, 384.f, 768.f, 256.f, 512.f, 1024.f, 352.f, 704.f, 1408.f};
#pragma unroll
    for (int a = 0; a < 9; ++a) {
        float score = e[9 + a] / s;
        float wa = AW[a], ha = AH[a];
        float cxa = __fadd_rn(shx, 7.5f), cya = __fadd_rn(shy, 7.5f);
        float dx = d[18 + 4 * a], dyy = d[19 + 4 * a];
        float dw = d[20 + 4 * a], dh = d[21 + 4 * a];
        float cx = __fadd_rn(__fmul_rn(dx, wa), cxa);
        float cy = __fadd_rn(__fmul_rn(dyy, ha), cya);
        float pw = __fmul_rn(wa, exp_xla(dw));
        float ph = __fmul_rn(ha, exp_xla(dh));
        float hx = __fmul_rn(0.5f, pw), hy = __fmul_rn(0.5f, ph);
        float x1 = fminf(fmaxf(__fsub_rn(cx, hx), 0.f), 4095.f);
        float y1 = fminf(fmaxf(__fsub_rn(cy, hy), 0.f), 4095.f);
        float x2 = fminf(fmaxf(__fadd_rn(cx, hx), 0.f), 4095.f);
        float y2 = fminf(fmaxf(__fadd_rn(cy, hy), 0.f), 4095.f);
        float vw = __fadd_rn(__fsub_rn(x2, x1), 1.0f);
        float vh = __fadd_rn(__fsub_rn(y2, y1), 1.0f);
        bool valid = (vw >= 16.0f) && (vh >= 16.0f);
        int i = pix * 9 + a;
        boxes[i] = make_float4(x1, y1, x2, y2);
        u64 k;
        if (valid) {
            u32 b = __float_as_uint(score);
            k = ((u64)(u32)~(b | 0x80000000u) << 32) | (u32)i;
        } else {
            k = (0xFFFFFFFFULL << 32) | (u32)i;
        }
        keys[i] = k;
    }
}

// ---------------- radix select: 8 passes of 8 bits, LDS histograms -----------
__global__ __launch_bounds__(256) void hist8(const u64* __restrict__ keys,
                                             u32* __restrict__ ghist,
                                             const u64* __restrict__ pfx, int pass) {
    __shared__ u32 lh[256];
    lh[threadIdx.x] = 0;
    __syncthreads();
    const u64 pref = *pfx;
    const int shift = 56 - 8 * pass;
    for (int i = blockIdx.x * 256 + threadIdx.x; i < 147456; i += 64 * 256) {
        u64 k = keys[i];
        bool match = (pass == 0) || ((k >> (shift + 8)) == pref);
        if (match) atomicAdd(&lh[(u32)(k >> shift) & 0xFFu], 1u);
    }
    __syncthreads();
    if (lh[threadIdx.x]) atomicAdd(&ghist[threadIdx.x], lh[threadIdx.x]);
}

__global__ __launch_bounds__(256) void scan8(const u32* __restrict__ ghist,
                                             u64* pfx, u32* tgt, int pass) {
    __shared__ u32 h[256];
    __shared__ u32 incl[256];
    const int t = threadIdx.x;
    u32 target = (pass == 0) ? 6000u : *tgt;
    u64 p0 = (pass == 0) ? 0ULL : *pfx;
    h[t] = ghist[t];
    incl[t] = h[t];
    __syncthreads();
    for (int off = 1; off < 256; off <<= 1) {
        u32 v = (t >= off) ? incl[t - off] : 0u;
        __syncthreads();
        incl[t] += v;
        __syncthreads();
    }
    u32 before = incl[t] - h[t];
    if (before < target && target <= incl[t]) {
        *pfx = (p0 << 8) | (u64)t;
        *tgt = target - before;
    }
}

__global__ void compact(const u64* __restrict__ keys, const u64* __restrict__ kstar,
                        u32* count, u64* __restrict__ ckey, u32* __restrict__ cidx) {
    int i = blockIdx.x * 256 + threadIdx.x;
    if (i >= 147456) return;
    u64 k = keys[i];
    if (k <= *kstar) {
        u32 pos = atomicAdd(count, 1u);
        if (pos < 6144) { ckey[pos] = k; cidx[pos] = (u32)(k & 0xFFFFFFFFu); }
    }
}

// ---------------- exact rank (keys unique) + gather sorted top-6000 ----------
__global__ __launch_bounds__(256) void rank_scatter(const u64* __restrict__ ckey,
                                                    const u32* __restrict__ cidx,
                                                    const u32* __restrict__ count,
                                                    const float4* __restrict__ boxes,
                                                    float4* __restrict__ tb,
                                                    float* __restrict__ tsc) {
    __shared__ u64 LK[6144];
    int N = (int)*count; if (N > 6144) N = 6144;
    for (int i = threadIdx.x; i < N; i += 256) LK[i] = ckey[i];
    __syncthreads();
    int e = blockIdx.x * 256 + threadIdx.x;
    if (e >= N) return;
    u64 myK = LK[e];
    u32 myI = cidx[e];
    int rank = 0;
    for (int c = 0; c < N; ++c) rank += (LK[c] < myK);
    if (rank < 6000) {
        tb[rank] = boxes[myI];
        u32 hi = (u32)(myK >> 32);
        tsc[rank] = (hi == 0xFFFFFFFFu) ? -__builtin_inff()
                                        : __uint_as_float(~hi & 0x7FFFFFFFu);
    }
}

// ---------------- alive bitmask init -----------------------------------------
__global__ void alive_init(const float* __restrict__ tsc, u64* __restrict__ alive0) {
    int r = blockIdx.x * 256 + threadIdx.x;
    bool a = false;
    if (r < 6000) a = tsc[r] > -__builtin_inff();
    u64 b = __ballot(a);
    if ((threadIdx.x & 63) == 0) alive0[r >> 6] = b;
}

// ---------------- suppression bitmask: m[j][i] = iou(tb[j],tb[i]) > 0.7 ------
__global__ __launch_bounds__(256) void nms_mask(const float4* __restrict__ tb,
                                                u64* __restrict__ mask) {
    int tid = blockIdx.x * 256 + threadIdx.x;
    if (tid >= 6000 * 94) return;
    int j = tid / 94, w = tid % 94;
    float4 bj = tb[j];
    float arJ = __fmul_rn(__fadd_rn(__fsub_rn(bj.z, bj.x), 1.0f),
                          __fadd_rn(__fsub_rn(bj.w, bj.y), 1.0f));
    u64 m = 0;
    int base = w * 64;
#pragma unroll 4
    for (int b = 0; b < 64; ++b) {
        int i = base + b;
        if (i >= 6000) break;
        float4 bi = tb[i];
        float arI = __fmul_rn(__fadd_rn(__fsub_rn(bi.z, bi.x), 1.0f),
                              __fadd_rn(__fsub_rn(bi.w, bi.y), 1.0f));
        float xx1 = fmaxf(bj.x, bi.x), yy1 = fmaxf(bj.y, bi.y);
        float xx2 = fminf(bj.z, bi.z), yy2 = fminf(bj.w, bi.w);
        float ww = fmaxf(__fadd_rn(__fsub_rn(xx2, xx1), 1.0f), 0.0f);
        float hh = fmaxf(__fadd_rn(__fsub_rn(yy2, yy1), 1.0f), 0.0f);
        float inter = __fmul_rn(ww, hh);
        float uni = __fsub_rn(__fadd_rn(arJ, arI), inter);
        float iou = inter / uni;
        if (iou > 0.7f) m |= (1ULL << b);
    }
    mask[(size_t)j * 96 + w] = m;
}

// ---------------- sequential NMS v2: LDS sliding window + deferred output ----
__global__ __launch_bounds__(64, 1) void nms_seq(const u64* __restrict__ alive0,
                                                 const u64* __restrict__ mask,
                                                 const float4* __restrict__ tb,
                                                 float* __restrict__ out) {
    __shared__ __align__(16) u64 lwin[64 * 96];   // 48 KB: rows [base, base+64)
    __shared__ u32 sel[1000];
    const int lane = threadIdx.x;
    u64 wl = alive0[lane];
    u64 wh = (lane < 30) ? alive0[64 + lane] : 0ULL;
    int base = -1000000;   // force refill on first selection
    int k = 0;
    for (; k < 1000; ++k) {
        // ---- j = first alive (strictly increasing across iterations) ----
        int j;
        {
            u64 blo = __ballot(wl != 0ULL);
            if (blo) {
                int l = __ffsll((long long)blo) - 1;
                u64 w = __shfl(wl, l);
                j = l * 64 + __ffsll((long long)w) - 1;
            } else {
                u64 bhi = __ballot(wh != 0ULL);
                if (!bhi) break;  // exhausted: remaining out rows stay 0
                int l = __ffsll((long long)bhi) - 1;
                u64 w = __shfl(wh, l);
                j = (64 + l) * 64 + __ffsll((long long)w) - 1;
            }
        }
        if (lane == 0) sel[k] = (u32)j;
        // ---- window: LDS hit, or bulk refill [j, j+64) (uniform branch) ----
        int s = j - base;
        if (s < 0 || s >= 64) {
            const char* gsrc = (const char*)mask + (size_t)j * 768 + (size_t)lane * 16;
            char* ldst = (char*)lwin;
#pragma unroll
            for (int i = 0; i < 48; ++i)
                gload_lds16(gsrc + (size_t)i * 1024, ldst + i * 1024);
            base = j;
            s = 0;
            asm volatile("s_waitcnt vmcnt(0)" ::: "memory");
        }
        u64 rl = lwin[(size_t)s * 96 + lane];
        u64 rh = (lane < 30) ? lwin[(size_t)s * 96 + 64 + lane] : 0ULL;
        // ---- apply row j (kills j itself via iou==1) ----
        wl &= ~rl;
        if (lane < 30) wh &= ~rh;
    }
    // ---- bulk gather: rois[k] = (0, tb[sel[k]]) — off the serial path ----
    __syncthreads();
    for (int r = lane; r < k; r += 64) {
        int j = (int)sel[r];
        float4 bj = tb[j];
        out[r * 5 + 1] = bj.x;
        out[r * 5 + 2] = bj.y;
        out[r * 5 + 3] = bj.z;
        out[r * 5 + 4] = bj.w;
    }
}

// ---------------- host ----------------
extern "C" void kernel_launch(void* const* d_in, const int* in_sizes, int n_in,
                              void* d_out, int out_size, void* d_ws, size_t ws_size,
                              hipStream_t stream) {
    const float *feat = nullptr, *rpn_w = nullptr, *rpn_b = nullptr;
    const float *cls_w = nullptr, *cls_b = nullptr, *box_w = nullptr, *box_b = nullptr;
    for (int i = 0; i < n_in; ++i) {
        switch (in_sizes[i]) {
            case 4194304: feat  = (const float*)d_in[i]; break;
            case 589824:  rpn_w = (const float*)d_in[i]; break;
            case 256:     rpn_b = (const float*)d_in[i]; break;
            case 4608:    cls_w = (const float*)d_in[i]; break;
            case 18:      cls_b = (const float*)d_in[i]; break;
            case 9216:    box_w = (const float*)d_in[i]; break;
            case 36:      box_b = (const float*)d_in[i]; break;
            default: break;  // image dims hardcoded (4096)
        }
    }

    char* w = (char*)d_ws;
    u64* pfx       = (u64*)(w + OFF_CTL);
    u32* tgt       = (u32*)(w + OFF_CTL + 8);
    u32* ctlCount  = (u32*)(w + OFF_CTL + 12);
    u32* hist      = (u32*)(w + OFF_HIST);
    float* dots    = (float*)(w + OFF_DOTS);
    float* wcv     = (float*)(w + OFF_WCV);
    float* xd      = (float*)(w + OFF_XD);
    float4* boxes  = (float4*)(w + OFF_BOX);
    u64* keys      = (u64*)(w + OFF_KEYS);
    u64* ckey      = (u64*)(w + OFF_CKEY);
    u32* cidx      = (u32*)(w + OFF_CIDX);
    float4* tb     = (float4*)(w + OFF_TB);
    float* tsc     = (float*)(w + OFF_TSC);
    u64* alive0    = (u64*)(w + OFF_ALIVE);
    u64* mask      = (u64*)(w + OFF_MASK);
    float* featP   = (float*)(w + OFF_FPAD);

    hipMemsetAsync(d_ws, 0, OFF_HIST + 8 * 256 * 4, stream);  // ctl + 8 hists
    hipMemsetAsync(d_out, 0, (size_t)out_size * sizeof(float), stream);

    prep_wcv<<<2304, 256, 0, stream>>>(rpn_w, wcv);
    prep_pad<<<17160, 256, 0, stream>>>(feat, featP);
    conv3x3<<<512, 256, 0, stream>>>(featP, wcv, rpn_b, xd);
    heads_seq<<<4096, 256, 0, stream>>>(xd, cls_w, box_w, dots);
    decode<<<64, 256, 0, stream>>>(dots, cls_b, box_b, boxes, keys);
    for (int p = 0; p < 8; ++p) {
        hist8<<<64, 256, 0, stream>>>(keys, hist + p * 256, pfx, p);
        scan8<<<1, 256, 0, stream>>>(hist + p * 256, pfx, tgt, p);
    }
    compact<<<576, 256, 0, stream>>>(keys, pfx, ctlCount, ckey, cidx);
    rank_scatter<<<24, 256, 0, stream>>>(ckey, cidx, ctlCount, boxes, tb, tsc);
    alive_init<<<24, 256, 0, stream>>>(tsc, alive0);
    nms_mask<<<2204, 256, 0, stream>>>(tb, mask);
    nms_seq<<<1, 64, 0, stream>>>(alive0, mask, tb, (float*)d_out);
}

// Round 5
// 932.030 us; speedup vs baseline: 1.3429x; 1.0047x over previous
//
#include <hip/hip_runtime.h>
#include <stdint.h>
#include <math.h>

typedef unsigned long long u64;
typedef unsigned int u32;
typedef float float4a __attribute__((ext_vector_type(4), aligned(4)));

// ---------------- workspace layout (bytes) ----------------
static const size_t OFF_CTL   = 0;          // [0]=u64 prefix/kstar, [8]=u32 target, [12]=u32 count
static const size_t OFF_HIST  = 1024;       // 8 passes * 256 * 4 = 8 KB
static const size_t OFF_DOTS  = 1049600;    // 16384*54*4
static const size_t OFF_WCV   = 4588544;    // 589824*4  [tap][ic][oc]
static const size_t OFF_XD    = 6947840;    // 16384*256*4 (conv out f32, HWC)
static const size_t OFF_BOX   = 23725056;   // 147456*16 (float4)
static const size_t OFF_KEYS  = 26084352;   // 147456*8
static const size_t OFF_CKEY  = 27264000;   // 6144*8
static const size_t OFF_CIDX  = 27313152;   // 6144*4
static const size_t OFF_TB    = 27337728;   // 6000*16
static const size_t OFF_TSC   = 27433728;   // 6000*4
static const size_t OFF_ALIVE = 27458048;   // 128*8
static const size_t OFF_MASK  = 27459072;   // 6000*96*8 = 4608000
static const size_t OFF_FPAD  = 32067584;   // 256*130*132*4 = 17571840  end ~49.6 MB

// XLA-CPU / Eigen / Cephes f32 exp (FMA form) — bit-matches the np reference.
__device__ __forceinline__ float exp_xla(float x) {
    float m = floorf(__fmaf_rn(x, 1.44269504088896341f, 0.5f));
    float r = __fmaf_rn(m, -0.693359375f, x);
    r = __fmaf_rn(m, 2.12194440e-4f, r);
    float r2 = r * r;
    float p = 1.9875691500e-4f;
    p = __fmaf_rn(p, r, 1.3981999507e-3f);
    p = __fmaf_rn(p, r, 8.3334519073e-3f);
    p = __fmaf_rn(p, r, 4.1665795894e-2f);
    p = __fmaf_rn(p, r, 1.6666665459e-1f);
    p = __fmaf_rn(p, r, 5.0000001201e-1f);
    p = __fmaf_rn(p, r2, r);
    p = __fadd_rn(p, 1.0f);
    int mi = (int)m;
    return p * __int_as_float((mi + 127) << 23);
}

// async global->LDS, 16B per lane, wave-uniform LDS base + lane*16
__device__ __forceinline__ void gload_lds16(const void* g, void* l) {
    __builtin_amdgcn_global_load_lds(
        (const __attribute__((address_space(1))) void*)g,
        (__attribute__((address_space(3))) void*)l, 16, 0, 0);
}

// ---------------- weight prep: rpn_w [oc][ic][tap] -> f32 [tap][ic][oc] ------
__global__ void prep_wcv(const float* __restrict__ rpn_w, float* __restrict__ wcv) {
    int t = blockIdx.x * 256 + threadIdx.x;
    if (t >= 589824) return;
    int tap = t / 65536, rem = t % 65536, ic = rem / 256, oc = rem % 256;
    wcv[t] = rpn_w[oc * 2304 + ic * 9 + tap];
}

// ---------------- feature pad: featP[ic][130][132], +1 halo of literal zeros -
__global__ void prep_pad(const float* __restrict__ feat, float* __restrict__ featP) {
    int t = blockIdx.x * 256 + threadIdx.x;
    if (t >= 256 * 130 * 132) return;
    int ic = t / 17160, rem = t % 17160, y = rem / 132, x = rem % 132;
    int sy = y - 1, sx = x - 1;
    float v = 0.f;
    if (sy >= 0 && sy < 128 && sx >= 0 && sx < 128)
        v = feat[ic * 16384 + sy * 128 + sx];
    featP[t] = v;
}

// ---------------- conv3x3 v5: 4px x 16oc per thread — vmem/FMA halved again --
// R4 confirmed vmem-per-FMA is the lever (v4: 1 load/32FMA -> 309us, 58% busy).
// v5: wave = 16 oc x 256 px -> per iter: 1 global dwordx4 + 4 LDS broadcast
// + 64 FMA (128cy). Total waves 1024 = 1 wave/SIMD (occupancy is NOT the
// limiter per R2; long FMA runs are). unroll 8 -> 1024cy FMA bodies cover the
// ~150cy L1 latency of the 8 hoisted loads. sW 64KB, 1 block/CU.
// Per-output chain UNCHANGED (tap-major, ic 0..255 ascending, one f32 acc,
// __fmaf_rn) -> bit-exact.
__global__ __launch_bounds__(256, 1) void conv3x3(const float* __restrict__ featP,
                                                  const float* __restrict__ wcv,
                                                  const float* __restrict__ rpn_b,
                                                  float* __restrict__ xd) {
    __shared__ float sW[16384];                // [ic][64 oc] for current tap
    const int band = blockIdx.x & 7;           // tile row (XCD-pinned)
    const int tx = (blockIdx.x >> 3) & 7;      // tile col
    const int ocb = blockIdx.x >> 6;           // 0..3, oc-block(64)
    const int oc0 = ocb * 64;
    const int tid = threadIdx.x;
    const int wid = tid >> 6;                  // wave 0..3 -> 16 oc each
    const int lane = tid & 63;
    const int py = lane >> 2, px0 = (lane & 3) * 4;   // wave covers 16x16 px
    const int gy = band * 16 + py, gx0 = tx * 16 + px0;
    const int ocB = oc0 + wid * 16;
    float acc[4][16];
#pragma unroll
    for (int p = 0; p < 4; ++p)
#pragma unroll
        for (int o = 0; o < 16; ++o) acc[p][o] = 0.f;
#pragma unroll
    for (int tap = 0; tap < 9; ++tap) {        // k-major: tap (ky,kx)
        __syncthreads();
        for (int idx = tid; idx < 4096; idx += 256) {      // 64KB, float4
            int ic = idx >> 4, oq = idx & 15;
            *(float4a*)&sW[ic * 64 + oq * 4] =
                *(const float4a*)&wcv[tap * 65536 + ic * 256 + oc0 + oq * 4];
        }
        __syncthreads();
        const float* fp = featP + (size_t)(gy + tap / 3) * 132 + (gx0 + tap % 3);
        const float* wl = sW + wid * 16;       // wave-uniform -> LDS broadcast
#pragma unroll 8
        for (int ic = 0; ic < 256; ++ic) {     // k-minor: ic ascending
            float4a fA = *(const float4a*)(fp + (size_t)ic * 17160);
            float4a w0 = *(const float4a*)(wl + ic * 64);
            float4a w1 = *(const float4a*)(wl + ic * 64 + 4);
            float4a w2 = *(const float4a*)(wl + ic * 64 + 8);
            float4a w3 = *(const float4a*)(wl + ic * 64 + 12);
#pragma unroll
            for (int p = 0; p < 4; ++p) {
#pragma unroll
                for (int o = 0; o < 4; ++o)
                    acc[p][o] = __fmaf_rn(fA[p], w0[o], acc[p][o]);
#pragma unroll
                for (int o = 0; o < 4; ++o)
                    acc[p][4 + o] = __fmaf_rn(fA[p], w1[o], acc[p][4 + o]);
#pragma unroll
                for (int o = 0; o < 4; ++o)
                    acc[p][8 + o] = __fmaf_rn(fA[p], w2[o], acc[p][8 + o]);
#pragma unroll
                for (int o = 0; o < 4; ++o)
                    acc[p][12 + o] = __fmaf_rn(fA[p], w3[o], acc[p][12 + o]);
            }
        }
    }
#pragma unroll
    for (int p = 0; p < 4; ++p) {
        float* op = xd + (size_t)(gy * 128 + gx0 + p) * 256 + ocB;
#pragma unroll
        for (int o = 0; o < 16; ++o) {
            float v = __fadd_rn(acc[p][o], rpn_b[ocB + o]);
            op[o] = v > 0.f ? v : 0.f;
        }
    }
}

// ---------------- heads: 1x1 convs, k=ic sequential f32 FMA (float4 loads) ---
__global__ __launch_bounds__(256, 1) void heads_seq(const float* __restrict__ xd,
                                                    const float* __restrict__ cls_w,
                                                    const float* __restrict__ box_w,
                                                    float* __restrict__ dots) {
    __shared__ float sX[4][260];
    const int tid = threadIdx.x;
    const int pix0 = blockIdx.x * 4;
    for (int idx = tid; idx < 1024; idx += 256)
        sX[idx >> 8][idx & 255] = xd[(size_t)(pix0 + (idx >> 8)) * 256 + (idx & 255)];
    __syncthreads();
    if (tid < 216) {
        const int pl = tid / 54, o = tid % 54;
        const float* wr = (o < 18) ? (cls_w + o * 256) : (box_w + (o - 18) * 256);
        const float4* x4 = (const float4*)&sX[pl][0];
        const float4* w4 = (const float4*)wr;
        float acc = 0.f;
        for (int q = 0; q < 64; ++q) {
            float4 xv = x4[q];
            float4 wv = w4[q];
            acc = __fmaf_rn(xv.x, wv.x, acc);
            acc = __fmaf_rn(xv.y, wv.y, acc);
            acc = __fmaf_rn(xv.z, wv.z, acc);
            acc = __fmaf_rn(xv.w, wv.w, acc);
        }
        dots[(size_t)(pix0 + pl) * 54 + o] = acc;
    }
}

// ---------------- decode: stepwise-F32 softmax + box decode, XLA exp ---------
__global__ __launch_bounds__(256, 1) void decode(const float* __restrict__ dots,
                                                 const float* __restrict__ cls_b,
                                                 const float* __restrict__ box_b,
                                                 float4* __restrict__ boxes,
                                                 u64* __restrict__ keys) {
    const int pix = blockIdx.x * 256 + threadIdx.x;
    if (pix >= 16384) return;
    const float* dt = dots + (size_t)pix * 54;
    float d[54];
#pragma unroll
    for (int i = 0; i < 54; ++i)
        d[i] = __fadd_rn(dt[i], (i < 18 ? cls_b[i] : box_b[i - 18]));
    float m = d[0];
#pragma unroll
    for (int i = 1; i < 18; ++i) m = fmaxf(m, d[i]);
    float e[18];
#pragma unroll
    for (int i = 0; i < 18; ++i) e[i] = exp_xla(__fsub_rn(d[i], m));
    float s = e[0];
#pragma unroll
    for (int i = 1; i < 18; ++i) s = __fadd_rn(s, e[i]);
    const int y = pix >> 7, x = pix & 127;
    const float shx = (float)(x * 32), shy = (float)(y * 32);
    const float AW[9] = {368.f, 736.f, 1472.f, 256.f, 512.f, 1024.f, 176.f, 352.f, 704.f};
    const float AH[9] = {192.f, 384.f, 768.f, 256.f, 512.f, 1024.f, 352.f, 704.f, 1408.f};
#pragma unroll
    for (int a = 0; a < 9; ++a) {
        float score = e[9 + a] / s;
        float wa = AW[a], ha = AH[a];
        float cxa = __fadd_rn(shx, 7.5f), cya = __fadd_rn(shy, 7.5f);
        float dx = d[18 + 4 * a], dyy = d[19 + 4 * a];
        float dw = d[20 + 4 * a], dh = d[21 + 4 * a];
        float cx = __fadd_rn(__fmul_rn(dx, wa), cxa);
        float cy = __fadd_rn(__fmul_rn(dyy, ha), cya);
        float pw = __fmul_rn(wa, exp_xla(dw));
        float ph = __fmul_rn(ha, exp_xla(dh));
        float hx = __fmul_rn(0.5f, pw), hy = __fmul_rn(0.5f, ph);
        float x1 = fminf(fmaxf(__fsub_rn(cx, hx), 0.f), 4095.f);
        float y1 = fminf(fmaxf(__fsub_rn(cy, hy), 0.f), 4095.f);
        float x2 = fminf(fmaxf(__fadd_rn(cx, hx), 0.f), 4095.f);
        float y2 = fminf(fmaxf(__fadd_rn(cy, hy), 0.f), 4095.f);
        float vw = __fadd_rn(__fsub_rn(x2, x1), 1.0f);
        float vh = __fadd_rn(__fsub_rn(y2, y1), 1.0f);
        bool valid = (vw >= 16.0f) && (vh >= 16.0f);
        int i = pix * 9 + a;
        boxes[i] = make_float4(x1, y1, x2, y2);
        u64 k;
        if (valid) {
            u32 b = __float_as_uint(score);
            k = ((u64)(u32)~(b | 0x80000000u) << 32) | (u32)i;
        } else {
            k = (0xFFFFFFFFULL << 32) | (u32)i;
        }
        keys[i] = k;
    }
}

// ---------------- radix select: 8 passes of 8 bits, LDS histograms -----------
__global__ __launch_bounds__(256) void hist8(const u64* __restrict__ keys,
                                             u32* __restrict__ ghist,
                                             const u64* __restrict__ pfx, int pass) {
    __shared__ u32 lh[256];
    lh[threadIdx.x] = 0;
    __syncthreads();
    const u64 pref = *pfx;
    const int shift = 56 - 8 * pass;
    for (int i = blockIdx.x * 256 + threadIdx.x; i < 147456; i += 64 * 256) {
        u64 k = keys[i];
        bool match = (pass == 0) || ((k >> (shift + 8)) == pref);
        if (match) atomicAdd(&lh[(u32)(k >> shift) & 0xFFu], 1u);
    }
    __syncthreads();
    if (lh[threadIdx.x]) atomicAdd(&ghist[threadIdx.x], lh[threadIdx.x]);
}

__global__ __launch_bounds__(256) void scan8(const u32* __restrict__ ghist,
                                             u64* pfx, u32* tgt, int pass) {
    __shared__ u32 h[256];
    __shared__ u32 incl[256];
    const int t = threadIdx.x;
    u32 target = (pass == 0) ? 6000u : *tgt;
    u64 p0 = (pass == 0) ? 0ULL : *pfx;
    h[t] = ghist[t];
    incl[t] = h[t];
    __syncthreads();
    for (int off = 1; off < 256; off <<= 1) {
        u32 v = (t >= off) ? incl[t - off] : 0u;
        __syncthreads();
        incl[t] += v;
        __syncthreads();
    }
    u32 before = incl[t] - h[t];
    if (before < target && target <= incl[t]) {
        *pfx = (p0 << 8) | (u64)t;
        *tgt = target - before;
    }
}

__global__ void compact(const u64* __restrict__ keys, const u64* __restrict__ kstar,
                        u32* count, u64* __restrict__ ckey, u32* __restrict__ cidx) {
    int i = blockIdx.x * 256 + threadIdx.x;
    if (i >= 147456) return;
    u64 k = keys[i];
    if (k <= *kstar) {
        u32 pos = atomicAdd(count, 1u);
        if (pos < 6144) { ckey[pos] = k; cidx[pos] = (u32)(k & 0xFFFFFFFFu); }
    }
}

// ---------------- exact rank (keys unique) + gather sorted top-6000 ----------
__global__ __launch_bounds__(256) void rank_scatter(const u64* __restrict__ ckey,
                                                    const u32* __restrict__ cidx,
                                                    const u32* __restrict__ count,
                                                    const float4* __restrict__ boxes,
                                                    float4* __restrict__ tb,
                                                    float* __restrict__ tsc) {
    __shared__ u64 LK[6144];
    int N = (int)*count; if (N > 6144) N = 6144;
    for (int i = threadIdx.x; i < N; i += 256) LK[i] = ckey[i];
    __syncthreads();
    int e = blockIdx.x * 256 + threadIdx.x;
    if (e >= N) return;
    u64 myK = LK[e];
    u32 myI = cidx[e];
    int rank = 0;
    for (int c = 0; c < N; ++c) rank += (LK[c] < myK);
    if (rank < 6000) {
        tb[rank] = boxes[myI];
        u32 hi = (u32)(myK >> 32);
        tsc[rank] = (hi == 0xFFFFFFFFu) ? -__builtin_inff()
                                        : __uint_as_float(~hi & 0x7FFFFFFFu);
    }
}

// ---------------- alive bitmask init -----------------------------------------
__global__ void alive_init(const float* __restrict__ tsc, u64* __restrict__ alive0) {
    int r = blockIdx.x * 256 + threadIdx.x;
    bool a = false;
    if (r < 6000) a = tsc[r] > -__builtin_inff();
    u64 b = __ballot(a);
    if ((threadIdx.x & 63) == 0) alive0[r >> 6] = b;
}

// ---------------- suppression bitmask: m[j][i] = iou(tb[j],tb[i]) > 0.7 ------
__global__ __launch_bounds__(256) void nms_mask(const float4* __restrict__ tb,
                                                u64* __restrict__ mask) {
    int tid = blockIdx.x * 256 + threadIdx.x;
    if (tid >= 6000 * 94) return;
    int j = tid / 94, w = tid % 94;
    float4 bj = tb[j];
    float arJ = __fmul_rn(__fadd_rn(__fsub_rn(bj.z, bj.x), 1.0f),
                          __fadd_rn(__fsub_rn(bj.w, bj.y), 1.0f));
    u64 m = 0;
    int base = w * 64;
#pragma unroll 4
    for (int b = 0; b < 64; ++b) {
        int i = base + b;
        if (i >= 6000) break;
        float4 bi = tb[i];
        float arI = __fmul_rn(__fadd_rn(__fsub_rn(bi.z, bi.x), 1.0f),
                              __fadd_rn(__fsub_rn(bi.w, bi.y), 1.0f));
        float xx1 = fmaxf(bj.x, bi.x), yy1 = fmaxf(bj.y, bi.y);
        float xx2 = fminf(bj.z, bi.z), yy2 = fminf(bj.w, bi.w);
        float ww = fmaxf(__fadd_rn(__fsub_rn(xx2, xx1), 1.0f), 0.0f);
        float hh = fmaxf(__fadd_rn(__fsub_rn(yy2, yy1), 1.0f), 0.0f);
        float inter = __fmul_rn(ww, hh);
        float uni = __fsub_rn(__fadd_rn(arJ, arI), inter);
        float iou = inter / uni;
        if (iou > 0.7f) m |= (1ULL << b);
    }
    mask[(size_t)j * 96 + w] = m;
}

// ---------------- sequential NMS v3: double-buffered prefetched window -------
// v2 post-mortem estimate: hit path ~170cy but refills (~94 x ~1+ us of
// L2/L3-latency drain) dominate the residual. v3: after a window becomes
// current, immediately ISSUE the next 64 rows into the other 48KB buffer
// (no wait). ~10 selections later the overrun finds data resident; only a
// vmcnt(0) (usually already retired) sits on the critical path. Also replace
// __shfl (risk of ds_bpermute, ~120cy LDS) with 2x v_readlane (lane index is
// ballot-derived => SGPR-uniform).
__global__ __launch_bounds__(64, 1) void nms_seq(const u64* __restrict__ alive0,
                                                 const u64* __restrict__ mask,
                                                 const float4* __restrict__ tb,
                                                 float* __restrict__ out) {
    __shared__ __align__(16) u64 lwin[2][64 * 96];   // 2 x 48KB windows
    __shared__ u32 sel[1000];
    const int lane = threadIdx.x;
    u64 wl = alive0[lane];
    u64 wh = (lane < 30) ? alive0[64 + lane] : 0ULL;
    int base = -1000000;   // force refill on first selection
    int pbase = -1;        // prefetch window start (-1 = none), in buf[cur^1]
    int cur = 0;
    int k = 0;
    for (; k < 1000; ++k) {
        // ---- j = first alive (strictly increasing across iterations) ----
        int j;
        {
            u64 blo = __ballot(wl != 0ULL);
            if (blo) {
                int l = __ffsll((long long)blo) - 1;
                u32 a = __builtin_amdgcn_readlane((u32)wl, l);
                u32 b = __builtin_amdgcn_readlane((u32)(wl >> 32), l);
                u64 w = ((u64)b << 32) | (u64)a;
                j = l * 64 + __ffsll((long long)w) - 1;
            } else {
                u64 bhi = __ballot(wh != 0ULL);
                if (!bhi) break;  // exhausted: remaining out rows stay 0
                int l = __ffsll((long long)bhi) - 1;
                u32 a = __builtin_amdgcn_readlane((u32)wh, l);
                u32 b = __builtin_amdgcn_readlane((u32)(wh >> 32), l);
                u64 w = ((u64)b << 32) | (u64)a;
                j = (64 + l) * 64 + __ffsll((long long)w) - 1;
            }
        }
        if (lane == 0) sel[k] = (u32)j;
        // ---- window management (wave-uniform branch) ----
        if (j >= base + 64) {
            if (pbase >= 0 && j < pbase + 64) {
                // prefetched buffer covers j: just retire outstanding loads
                asm volatile("s_waitcnt vmcnt(0)" ::: "memory");
                cur ^= 1;
                base = pbase;
            } else {
                // jump past prefetch (or first iter): full refill into cur
                asm volatile("s_waitcnt vmcnt(0)" ::: "memory");
                const char* gsrc = (const char*)mask + (size_t)j * 768 + (size_t)lane * 16;
                char* ldst = (char*)&lwin[cur][0];
#pragma unroll
                for (int i = 0; i < 48; ++i)
                    gload_lds16(gsrc + (size_t)i * 1024, ldst + i * 1024);
                base = j;
                asm volatile("s_waitcnt vmcnt(0)" ::: "memory");
            }
            pbase = -1;
            if (base + 64 < 6000) {
                // issue prefetch of next window into the other buffer (NO wait)
                const char* gs2 = (const char*)mask + (size_t)(base + 64) * 768 + (size_t)lane * 16;
                char* ld2 = (char*)&lwin[cur ^ 1][0];
#pragma unroll
                for (int i = 0; i < 48; ++i)
                    gload_lds16(gs2 + (size_t)i * 1024, ld2 + i * 1024);
                pbase = base + 64;
            }
        }
        const int s = j - base;
        u64 rl = lwin[cur][(size_t)s * 96 + lane];
        u64 rh = (lane < 30) ? lwin[cur][(size_t)s * 96 + 64 + lane] : 0ULL;
        // ---- apply row j (kills j itself via iou==1) ----
        wl &= ~rl;
        if (lane < 30) wh &= ~rh;
    }
    // ---- bulk gather: rois[k] = (0, tb[sel[k]]) — off the serial path ----
    __syncthreads();
    for (int r = lane; r < k; r += 64) {
        int j = (int)sel[r];
        float4 bj = tb[j];
        out[r * 5 + 1] = bj.x;
        out[r * 5 + 2] = bj.y;
        out[r * 5 + 3] = bj.z;
        out[r * 5 + 4] = bj.w;
    }
}

// ---------------- host ----------------
extern "C" void kernel_launch(void* const* d_in, const int* in_sizes, int n_in,
                              void* d_out, int out_size, void* d_ws, size_t ws_size,
                              hipStream_t stream) {
    const float *feat = nullptr, *rpn_w = nullptr, *rpn_b = nullptr;
    const float *cls_w = nullptr, *cls_b = nullptr, *box_w = nullptr, *box_b = nullptr;
    for (int i = 0; i < n_in; ++i) {
        switch (in_sizes[i]) {
            case 4194304: feat  = (const float*)d_in[i]; break;
            case 589824:  rpn_w = (const float*)d_in[i]; break;
            case 256:     rpn_b = (const float*)d_in[i]; break;
            case 4608:    cls_w = (const float*)d_in[i]; break;
            case 18:      cls_b = (const float*)d_in[i]; break;
            case 9216:    box_w = (const float*)d_in[i]; break;
            case 36:      box_b = (const float*)d_in[i]; break;
            default: break;  // image dims hardcoded (4096)
        }
    }

    char* w = (char*)d_ws;
    u64* pfx       = (u64*)(w + OFF_CTL);
    u32* tgt       = (u32*)(w + OFF_CTL + 8);
    u32* ctlCount  = (u32*)(w + OFF_CTL + 12);
    u32* hist      = (u32*)(w + OFF_HIST);
    float* dots    = (float*)(w + OFF_DOTS);
    float* wcv     = (float*)(w + OFF_WCV);
    float* xd      = (float*)(w + OFF_XD);
    float4* boxes  = (float4*)(w + OFF_BOX);
    u64* keys      = (u64*)(w + OFF_KEYS);
    u64* ckey      = (u64*)(w + OFF_CKEY);
    u32* cidx      = (u32*)(w + OFF_CIDX);
    float4* tb     = (float4*)(w + OFF_TB);
    float* tsc     = (float*)(w + OFF_TSC);
    u64* alive0    = (u64*)(w + OFF_ALIVE);
    u64* mask      = (u64*)(w + OFF_MASK);
    float* featP   = (float*)(w + OFF_FPAD);

    hipMemsetAsync(d_ws, 0, OFF_HIST + 8 * 256 * 4, stream);  // ctl + 8 hists
    hipMemsetAsync(d_out, 0, (size_t)out_size * sizeof(float), stream);

    prep_wcv<<<2304, 256, 0, stream>>>(rpn_w, wcv);
    prep_pad<<<17160, 256, 0, stream>>>(feat, featP);
    conv3x3<<<256, 256, 0, stream>>>(featP, wcv, rpn_b, xd);
    heads_seq<<<4096, 256, 0, stream>>>(xd, cls_w, box_w, dots);
    decode<<<64, 256, 0, stream>>>(dots, cls_b, box_b, boxes, keys);
    for (int p = 0; p < 8; ++p) {
        hist8<<<64, 256, 0, stream>>>(keys, hist + p * 256, pfx, p);
        scan8<<<1, 256, 0, stream>>>(hist + p * 256, pfx, tgt, p);
    }
    compact<<<576, 256, 0, stream>>>(keys, pfx, ctlCount, ckey, cidx);
    rank_scatter<<<24, 256, 0, stream>>>(ckey, cidx, ctlCount, boxes, tb, tsc);
    alive_init<<<24, 256, 0, stream>>>(tsc, alive0);
    nms_mask<<<2204, 256, 0, stream>>>(tb, mask);
    nms_seq<<<1, 64, 0, stream>>>(alive0, mask, tb, (float*)d_out);
}

// Round 7
// 912.396 us; speedup vs baseline: 1.3718x; 1.0215x over previous
//
#include <hip/hip_runtime.h>
#include <stdint.h>
#include <math.h>

typedef unsigned long long u64;
typedef unsigned int u32;
typedef float float4a __attribute__((ext_vector_type(4), aligned(4)));

// ---------------- workspace layout (bytes) ----------------
static const size_t OFF_CTL   = 0;          // [0]=u64 prefix/kstar, [8]=u32 target, [12]=u32 count
static const size_t OFF_HIST  = 1024;       // 8 passes * 256 * 4 = 8 KB
static const size_t OFF_DOTS  = 1049600;    // 16384*54*4
static const size_t OFF_WCV   = 4588544;    // 589824*4  [tap][ic][oc]
static const size_t OFF_XD    = 6947840;    // 16384*256*4 (conv out f32, HWC)
static const size_t OFF_BOX   = 23725056;   // 147456*16 (float4)
static const size_t OFF_KEYS  = 26084352;   // 147456*8
static const size_t OFF_CKEY  = 27264000;   // 6144*8
static const size_t OFF_CIDX  = 27313152;   // 6144*4
static const size_t OFF_TB    = 27337728;   // 6000*16
static const size_t OFF_TSC   = 27433728;   // 6000*4
static const size_t OFF_ALIVE = 27458048;   // 128*8
static const size_t OFF_MASK  = 27459072;   // 6000*96*8 = 4608000
static const size_t OFF_FPAD  = 32067584;   // 256*130*132*4 = 17571840  end ~49.6 MB

// XLA-CPU / Eigen / Cephes f32 exp (FMA form) — bit-matches the np reference.
__device__ __forceinline__ float exp_xla(float x) {
    float m = floorf(__fmaf_rn(x, 1.44269504088896341f, 0.5f));
    float r = __fmaf_rn(m, -0.693359375f, x);
    r = __fmaf_rn(m, 2.12194440e-4f, r);
    float r2 = r * r;
    float p = 1.9875691500e-4f;
    p = __fmaf_rn(p, r, 1.3981999507e-3f);
    p = __fmaf_rn(p, r, 8.3334519073e-3f);
    p = __fmaf_rn(p, r, 4.1665795894e-2f);
    p = __fmaf_rn(p, r, 1.6666665459e-1f);
    p = __fmaf_rn(p, r, 5.0000001201e-1f);
    p = __fmaf_rn(p, r2, r);
    p = __fadd_rn(p, 1.0f);
    int mi = (int)m;
    return p * __int_as_float((mi + 127) << 23);
}

// async global->LDS, 16B per lane, wave-uniform LDS base + lane*16
__device__ __forceinline__ void gload_lds16(const void* g, void* l) {
    __builtin_amdgcn_global_load_lds(
        (const __attribute__((address_space(1))) void*)g,
        (__attribute__((address_space(3))) void*)l, 16, 0, 0);
}

// ---------------- weight prep: rpn_w [oc][ic][tap] -> f32 [tap][ic][oc] ------
__global__ void prep_wcv(const float* __restrict__ rpn_w, float* __restrict__ wcv) {
    int t = blockIdx.x * 256 + threadIdx.x;
    if (t >= 589824) return;
    int tap = t / 65536, rem = t % 65536, ic = rem / 256, oc = rem % 256;
    wcv[t] = rpn_w[oc * 2304 + ic * 9 + tap];
}

// ---------------- feature pad: featP[ic][130][132], +1 halo of literal zeros -
__global__ void prep_pad(const float* __restrict__ feat, float* __restrict__ featP) {
    int t = blockIdx.x * 256 + threadIdx.x;
    if (t >= 256 * 130 * 132) return;
    int ic = t / 17160, rem = t % 17160, y = rem / 132, x = rem % 132;
    int sy = y - 1, sx = x - 1;
    float v = 0.f;
    if (sy >= 0 && sy < 128 && sx >= 0 && sx < 128)
        v = feat[ic * 16384 + sy * 128 + sx];
    featP[t] = v;
}

// ---------------- conv3x3 v4 (PROVEN, R4: 309us): 4px x 8oc per thread -------
// R6 post-mortem: v6's scalar (s_load/K$) weight path caused post-timing
// divergence under graph replay + workspace re-poisoning — reverted to the
// LDS-broadcast weight path, which is replay-safe (verified R4/R5).
// Wave = ONE oc-group of 8 oc covering all 256 px -> per iter:
// 1 global dwordx4 + 2 LDS broadcast b128 + 32 FMA. Per-output chain
// (tap-major, ic 0..255 ascending, one f32 acc, __fmaf_rn) -> bit-exact.
__global__ __launch_bounds__(256, 2) void conv3x3(const float* __restrict__ featP,
                                                  const float* __restrict__ wcv,
                                                  const float* __restrict__ rpn_b,
                                                  float* __restrict__ xd) {
    __shared__ float sW[8192];                 // [ic][32 oc] for current tap
    const int band = blockIdx.x & 7;           // tile row (XCD-pinned)
    const int slot = blockIdx.x >> 3;          // 0..63
    const int tx = slot & 7, ocb = slot >> 3;  // tile col, oc-block(32)
    const int oc0 = ocb * 32;
    const int tid = threadIdx.x;
    const int wid = tid >> 6;                  // wave 0..3 -> 8 oc each
    const int lane = tid & 63;
    const int py = lane >> 2, px0 = (lane & 3) * 4;   // wave covers 16x16 px
    const int gy = band * 16 + py, gx0 = tx * 16 + px0;
    const int ocB = oc0 + wid * 8;
    float acc[4][8];
#pragma unroll
    for (int p = 0; p < 4; ++p)
#pragma unroll
        for (int o = 0; o < 8; ++o) acc[p][o] = 0.f;
#pragma unroll
    for (int tap = 0; tap < 9; ++tap) {        // k-major: tap (ky,kx)
        __syncthreads();
        for (int idx = tid; idx < 8192; idx += 256)
            sW[idx] = wcv[tap * 65536 + (idx >> 5) * 256 + oc0 + (idx & 31)];
        __syncthreads();
        const float* fp = featP + (size_t)(gy + tap / 3) * 132 + (gx0 + tap % 3);
        const float* wl = sW + wid * 8;        // wave-uniform -> LDS broadcast
#pragma unroll 4
        for (int ic = 0; ic < 256; ++ic) {     // k-minor: ic ascending
            float4a fA = *(const float4a*)(fp + (size_t)ic * 17160);
            float4a w0 = *(const float4a*)(wl + ic * 32);
            float4a w1 = *(const float4a*)(wl + ic * 32 + 4);
#pragma unroll
            for (int p = 0; p < 4; ++p) {
#pragma unroll
                for (int o = 0; o < 4; ++o)
                    acc[p][o] = __fmaf_rn(fA[p], w0[o], acc[p][o]);
#pragma unroll
                for (int o = 0; o < 4; ++o)
                    acc[p][4 + o] = __fmaf_rn(fA[p], w1[o], acc[p][4 + o]);
            }
        }
    }
#pragma unroll
    for (int p = 0; p < 4; ++p) {
        float* op = xd + (size_t)(gy * 128 + gx0 + p) * 256 + ocB;
#pragma unroll
        for (int o = 0; o < 8; ++o) {
            float v = __fadd_rn(acc[p][o], rpn_b[ocB + o]);
            op[o] = v > 0.f ? v : 0.f;
        }
    }
}

// ---------------- heads: 1x1 convs, k=ic sequential f32 FMA (float4 loads) ---
__global__ __launch_bounds__(256, 1) void heads_seq(const float* __restrict__ xd,
                                                    const float* __restrict__ cls_w,
                                                    const float* __restrict__ box_w,
                                                    float* __restrict__ dots) {
    __shared__ float sX[4][260];
    const int tid = threadIdx.x;
    const int pix0 = blockIdx.x * 4;
    for (int idx = tid; idx < 1024; idx += 256)
        sX[idx >> 8][idx & 255] = xd[(size_t)(pix0 + (idx >> 8)) * 256 + (idx & 255)];
    __syncthreads();
    if (tid < 216) {
        const int pl = tid / 54, o = tid % 54;
        const float* wr = (o < 18) ? (cls_w + o * 256) : (box_w + (o - 18) * 256);
        const float4* x4 = (const float4*)&sX[pl][0];
        const float4* w4 = (const float4*)wr;
        float acc = 0.f;
        for (int q = 0; q < 64; ++q) {
            float4 xv = x4[q];
            float4 wv = w4[q];
            acc = __fmaf_rn(xv.x, wv.x, acc);
            acc = __fmaf_rn(xv.y, wv.y, acc);
            acc = __fmaf_rn(xv.z, wv.z, acc);
            acc = __fmaf_rn(xv.w, wv.w, acc);
        }
        dots[(size_t)(pix0 + pl) * 54 + o] = acc;
    }
}

// ---------------- decode: stepwise-F32 softmax + box decode, XLA exp ---------
__global__ __launch_bounds__(256, 1) void decode(const float* __restrict__ dots,
                                                 const float* __restrict__ cls_b,
                                                 const float* __restrict__ box_b,
                                                 float4* __restrict__ boxes,
                                                 u64* __restrict__ keys) {
    const int pix = blockIdx.x * 256 + threadIdx.x;
    if (pix >= 16384) return;
    const float* dt = dots + (size_t)pix * 54;
    float d[54];
#pragma unroll
    for (int i = 0; i < 54; ++i)
        d[i] = __fadd_rn(dt[i], (i < 18 ? cls_b[i] : box_b[i - 18]));
    float m = d[0];
#pragma unroll
    for (int i = 1; i < 18; ++i) m = fmaxf(m, d[i]);
    float e[18];
#pragma unroll
    for (int i = 0; i < 18; ++i) e[i] = exp_xla(__fsub_rn(d[i], m));
    float s = e[0];
#pragma unroll
    for (int i = 1; i < 18; ++i) s = __fadd_rn(s, e[i]);
    const int y = pix >> 7, x = pix & 127;
    const float shx = (float)(x * 32), shy = (float)(y * 32);
    const float AW[9] = {368.f, 736.f, 1472.f, 256.f, 512.f, 1024.f, 176.f, 352.f, 704.f};
    const float AH[9] = {192.f, 384.f, 768.f, 256.f, 512.f, 1024.f, 352.f, 704.f, 1408.f};
#pragma unroll
    for (int a = 0; a < 9; ++a) {
        float score = e[9 + a] / s;
        float wa = AW[a], ha = AH[a];
        float cxa = __fadd_rn(shx, 7.5f), cya = __fadd_rn(shy, 7.5f);
        float dx = d[18 + 4 * a], dyy = d[19 + 4 * a];
        float dw = d[20 + 4 * a], dh = d[21 + 4 * a];
        float cx = __fadd_rn(__fmul_rn(dx, wa), cxa);
        float cy = __fadd_rn(__fmul_rn(dyy, ha), cya);
        float pw = __fmul_rn(wa, exp_xla(dw));
        float ph = __fmul_rn(ha, exp_xla(dh));
        float hx = __fmul_rn(0.5f, pw), hy = __fmul_rn(0.5f, ph);
        float x1 = fminf(fmaxf(__fsub_rn(cx, hx), 0.f), 4095.f);
        float y1 = fminf(fmaxf(__fsub_rn(cy, hy), 0.f), 4095.f);
        float x2 = fminf(fmaxf(__fadd_rn(cx, hx), 0.f), 4095.f);
        float y2 = fminf(fmaxf(__fadd_rn(cy, hy), 0.f), 4095.f);
        float vw = __fadd_rn(__fsub_rn(x2, x1), 1.0f);
        float vh = __fadd_rn(__fsub_rn(y2, y1), 1.0f);
        bool valid = (vw >= 16.0f) && (vh >= 16.0f);
        int i = pix * 9 + a;
        boxes[i] = make_float4(x1, y1, x2, y2);
        u64 k;
        if (valid) {
            u32 b = __float_as_uint(score);
            k = ((u64)(u32)~(b | 0x80000000u) << 32) | (u32)i;
        } else {
            k = (0xFFFFFFFFULL << 32) | (u32)i;
        }
        keys[i] = k;
    }
}

// ---------------- radix select: 8 passes of 8 bits, LDS histograms -----------
__global__ __launch_bounds__(256) void hist8(const u64* __restrict__ keys,
                                             u32* __restrict__ ghist,
                                             const u64* __restrict__ pfx, int pass) {
    __shared__ u32 lh[256];
    lh[threadIdx.x] = 0;
    __syncthreads();
    const u64 pref = *pfx;
    const int shift = 56 - 8 * pass;
    for (int i = blockIdx.x * 256 + threadIdx.x; i < 147456; i += 64 * 256) {
        u64 k = keys[i];
        bool match = (pass == 0) || ((k >> (shift + 8)) == pref);
        if (match) atomicAdd(&lh[(u32)(k >> shift) & 0xFFu], 1u);
    }
    __syncthreads();
    if (lh[threadIdx.x]) atomicAdd(&ghist[threadIdx.x], lh[threadIdx.x]);
}

__global__ __launch_bounds__(256) void scan8(const u32* __restrict__ ghist,
                                             u64* pfx, u32* tgt, int pass) {
    __shared__ u32 h[256];
    __shared__ u32 incl[256];
    const int t = threadIdx.x;
    u32 target = (pass == 0) ? 6000u : *tgt;
    u64 p0 = (pass == 0) ? 0ULL : *pfx;
    h[t] = ghist[t];
    incl[t] = h[t];
    __syncthreads();
    for (int off = 1; off < 256; off <<= 1) {
        u32 v = (t >= off) ? incl[t - off] : 0u;
        __syncthreads();
        incl[t] += v;
        __syncthreads();
    }
    u32 before = incl[t] - h[t];
    if (before < target && target <= incl[t]) {
        *pfx = (p0 << 8) | (u64)t;
        *tgt = target - before;
    }
}

__global__ void compact(const u64* __restrict__ keys, const u64* __restrict__ kstar,
                        u32* count, u64* __restrict__ ckey, u32* __restrict__ cidx) {
    int i = blockIdx.x * 256 + threadIdx.x;
    if (i >= 147456) return;
    u64 k = keys[i];
    if (k <= *kstar) {
        u32 pos = atomicAdd(count, 1u);
        if (pos < 6144) { ckey[pos] = k; cidx[pos] = (u32)(k & 0xFFFFFFFFu); }
    }
}

// ---------------- exact rank (keys unique) + gather sorted top-6000 ----------
__global__ __launch_bounds__(256) void rank_scatter(const u64* __restrict__ ckey,
                                                    const u32* __restrict__ cidx,
                                                    const u32* __restrict__ count,
                                                    const float4* __restrict__ boxes,
                                                    float4* __restrict__ tb,
                                                    float* __restrict__ tsc) {
    __shared__ u64 LK[6144];
    int N = (int)*count; if (N > 6144) N = 6144;
    for (int i = threadIdx.x; i < N; i += 256) LK[i] = ckey[i];
    __syncthreads();
    int e = blockIdx.x * 256 + threadIdx.x;
    if (e >= N) return;
    u64 myK = LK[e];
    u32 myI = cidx[e];
    int rank = 0;
    for (int c = 0; c < N; ++c) rank += (LK[c] < myK);
    if (rank < 6000) {
        tb[rank] = boxes[myI];
        u32 hi = (u32)(myK >> 32);
        tsc[rank] = (hi == 0xFFFFFFFFu) ? -__builtin_inff()
                                        : __uint_as_float(~hi & 0x7FFFFFFFu);
    }
}

// ---------------- alive bitmask init -----------------------------------------
__global__ void alive_init(const float* __restrict__ tsc, u64* __restrict__ alive0) {
    int r = blockIdx.x * 256 + threadIdx.x;
    bool a = false;
    if (r < 6000) a = tsc[r] > -__builtin_inff();
    u64 b = __ballot(a);
    if ((threadIdx.x & 63) == 0) alive0[r >> 6] = b;
}

// ---------------- suppression bitmask: m[j][i] = iou(tb[j],tb[i]) > 0.7 ------
__global__ __launch_bounds__(256) void nms_mask(const float4* __restrict__ tb,
                                                u64* __restrict__ mask) {
    int tid = blockIdx.x * 256 + threadIdx.x;
    if (tid >= 6000 * 94) return;
    int j = tid / 94, w = tid % 94;
    float4 bj = tb[j];
    float arJ = __fmul_rn(__fadd_rn(__fsub_rn(bj.z, bj.x), 1.0f),
                          __fadd_rn(__fsub_rn(bj.w, bj.y), 1.0f));
    u64 m = 0;
    int base = w * 64;
#pragma unroll 4
    for (int b = 0; b < 64; ++b) {
        int i = base + b;
        if (i >= 6000) break;
        float4 bi = tb[i];
        float arI = __fmul_rn(__fadd_rn(__fsub_rn(bi.z, bi.x), 1.0f),
                              __fadd_rn(__fsub_rn(bi.w, bi.y), 1.0f));
        float xx1 = fmaxf(bj.x, bi.x), yy1 = fmaxf(bj.y, bi.y);
        float xx2 = fminf(bj.z, bi.z), yy2 = fminf(bj.w, bi.w);
        float ww = fmaxf(__fadd_rn(__fsub_rn(xx2, xx1), 1.0f), 0.0f);
        float hh = fmaxf(__fadd_rn(__fsub_rn(yy2, yy1), 1.0f), 0.0f);
        float inter = __fmul_rn(ww, hh);
        float uni = __fsub_rn(__fadd_rn(arJ, arI), inter);
        float iou = inter / uni;
        if (iou > 0.7f) m |= (1ULL << b);
    }
    mask[(size_t)j * 96 + w] = m;
}

// ---------------- sequential NMS v3b: dbuf prefetched window, IN-BOUNDS ------
// v3 + OOB hygiene: refill/prefetch window starts are clamped to row 5936 so
// the 48KB gload span [start, start+64) x 768B always stays inside mask
// (rows 0..5999). Rows requested with j>5936 land at s=j-5936<64. Otherwise
// identical to R5's passing version (readlane j-broadcast, deferred output).
__global__ __launch_bounds__(64, 1) void nms_seq(const u64* __restrict__ alive0,
                                                 const u64* __restrict__ mask,
                                                 const float4* __restrict__ tb,
                                                 float* __restrict__ out) {
    __shared__ __align__(16) u64 lwin[2][64 * 96];   // 2 x 48KB windows
    __shared__ u32 sel[1000];
    const int lane = threadIdx.x;
    u64 wl = alive0[lane];
    u64 wh = (lane < 30) ? alive0[64 + lane] : 0ULL;
    int base = -1000000;   // force refill on first selection
    int pbase = -1;        // prefetch window start (-1 = none), in buf[cur^1]
    int cur = 0;
    int k = 0;
    for (; k < 1000; ++k) {
        // ---- j = first alive (strictly increasing across iterations) ----
        int j;
        {
            u64 blo = __ballot(wl != 0ULL);
            if (blo) {
                int l = __ffsll((long long)blo) - 1;
                u32 a = __builtin_amdgcn_readlane((u32)wl, l);
                u32 b = __builtin_amdgcn_readlane((u32)(wl >> 32), l);
                u64 w = ((u64)b << 32) | (u64)a;
                j = l * 64 + __ffsll((long long)w) - 1;
            } else {
                u64 bhi = __ballot(wh != 0ULL);
                if (!bhi) break;  // exhausted: remaining out rows stay 0
                int l = __ffsll((long long)bhi) - 1;
                u32 a = __builtin_amdgcn_readlane((u32)wh, l);
                u32 b = __builtin_amdgcn_readlane((u32)(wh >> 32), l);
                u64 w = ((u64)b << 32) | (u64)a;
                j = (64 + l) * 64 + __ffsll((long long)w) - 1;
            }
        }
        if (lane == 0) sel[k] = (u32)j;
        // ---- window management (wave-uniform branch) ----
        if (j >= base + 64) {
            if (pbase >= 0 && j < pbase + 64) {
                // prefetched buffer covers j: just retire outstanding loads
                asm volatile("s_waitcnt vmcnt(0)" ::: "memory");
                cur ^= 1;
                base = pbase;
            } else {
                // jump past prefetch (or first iter): full refill into cur
                int js = (j > 5936) ? 5936 : j;     // clamp: stay inside mask
                asm volatile("s_waitcnt vmcnt(0)" ::: "memory");
                const char* gsrc = (const char*)mask + (size_t)js * 768 + (size_t)lane * 16;
                char* ldst = (char*)&lwin[cur][0];
#pragma unroll
                for (int i = 0; i < 48; ++i)
                    gload_lds16(gsrc + (size_t)i * 1024, ldst + i * 1024);
                base = js;
                asm volatile("s_waitcnt vmcnt(0)" ::: "memory");
            }
            pbase = -1;
            if (base + 64 < 6000) {
                // issue prefetch of next window into the other buffer (NO wait)
                int ps = (base + 64 > 5936) ? 5936 : (base + 64);  // clamp
                const char* gs2 = (const char*)mask + (size_t)ps * 768 + (size_t)lane * 16;
                char* ld2 = (char*)&lwin[cur ^ 1][0];
#pragma unroll
                for (int i = 0; i < 48; ++i)
                    gload_lds16(gs2 + (size_t)i * 1024, ld2 + i * 1024);
                pbase = ps;
            }
        }
        const int s = j - base;
        u64 rl = lwin[cur][(size_t)s * 96 + lane];
        u64 rh = (lane < 30) ? lwin[cur][(size_t)s * 96 + 64 + lane] : 0ULL;
        // ---- apply row j (kills j itself via iou==1) ----
        wl &= ~rl;
        if (lane < 30) wh &= ~rh;
    }
    // ---- bulk gather: rois[k] = (0, tb[sel[k]]) — off the serial path ----
    __syncthreads();
    for (int r = lane; r < k; r += 64) {
        int j = (int)sel[r];
        float4 bj = tb[j];
        out[r * 5 + 1] = bj.x;
        out[r * 5 + 2] = bj.y;
        out[r * 5 + 3] = bj.z;
        out[r * 5 + 4] = bj.w;
    }
}

// ---------------- host ----------------
extern "C" void kernel_launch(void* const* d_in, const int* in_sizes, int n_in,
                              void* d_out, int out_size, void* d_ws, size_t ws_size,
                              hipStream_t stream) {
    const float *feat = nullptr, *rpn_w = nullptr, *rpn_b = nullptr;
    const float *cls_w = nullptr, *cls_b = nullptr, *box_w = nullptr, *box_b = nullptr;
    for (int i = 0; i < n_in; ++i) {
        switch (in_sizes[i]) {
            case 4194304: feat  = (const float*)d_in[i]; break;
            case 589824:  rpn_w = (const float*)d_in[i]; break;
            case 256:     rpn_b = (const float*)d_in[i]; break;
            case 4608:    cls_w = (const float*)d_in[i]; break;
            case 18:      cls_b = (const float*)d_in[i]; break;
            case 9216:    box_w = (const float*)d_in[i]; break;
            case 36:      box_b = (const float*)d_in[i]; break;
            default: break;  // image dims hardcoded (4096)
        }
    }

    char* w = (char*)d_ws;
    u64* pfx       = (u64*)(w + OFF_CTL);
    u32* tgt       = (u32*)(w + OFF_CTL + 8);
    u32* ctlCount  = (u32*)(w + OFF_CTL + 12);
    u32* hist      = (u32*)(w + OFF_HIST);
    float* dots    = (float*)(w + OFF_DOTS);
    float* wcv     = (float*)(w + OFF_WCV);
    float* xd      = (float*)(w + OFF_XD);
    float4* boxes  = (float4*)(w + OFF_BOX);
    u64* keys      = (u64*)(w + OFF_KEYS);
    u64* ckey      = (u64*)(w + OFF_CKEY);
    u32* cidx      = (u32*)(w + OFF_CIDX);
    float4* tb     = (float4*)(w + OFF_TB);
    float* tsc     = (float*)(w + OFF_TSC);
    u64* alive0    = (u64*)(w + OFF_ALIVE);
    u64* mask      = (u64*)(w + OFF_MASK);
    float* featP   = (float*)(w + OFF_FPAD);

    hipMemsetAsync(d_ws, 0, OFF_HIST + 8 * 256 * 4, stream);  // ctl + 8 hists
    hipMemsetAsync(d_out, 0, (size_t)out_size * sizeof(float), stream);

    prep_wcv<<<2304, 256, 0, stream>>>(rpn_w, wcv);
    prep_pad<<<17160, 256, 0, stream>>>(feat, featP);
    conv3x3<<<512, 256, 0, stream>>>(featP, wcv, rpn_b, xd);
    heads_seq<<<4096, 256, 0, stream>>>(xd, cls_w, box_w, dots);
    decode<<<64, 256, 0, stream>>>(dots, cls_b, box_b, boxes, keys);
    for (int p = 0; p < 8; ++p) {
        hist8<<<64, 256, 0, stream>>>(keys, hist + p * 256, pfx, p);
        scan8<<<1, 256, 0, stream>>>(hist + p * 256, pfx, tgt, p);
    }
    compact<<<576, 256, 0, stream>>>(keys, pfx, ctlCount, ckey, cidx);
    rank_scatter<<<24, 256, 0, stream>>>(ckey, cidx, ctlCount, boxes, tb, tsc);
    alive_init<<<24, 256, 0, stream>>>(tsc, alive0);
    nms_mask<<<2204, 256, 0, stream>>>(tb, mask);
    nms_seq<<<1, 64, 0, stream>>>(alive0, mask, tb, (float*)d_out);
}

// Round 10
// 904.610 us; speedup vs baseline: 1.3836x; 1.0086x over previous
//
#include <hip/hip_runtime.h>
#include <stdint.h>
#include <math.h>

typedef unsigned long long u64;
typedef unsigned int u32;
typedef float float4a __attribute__((ext_vector_type(4), aligned(4)));
typedef unsigned long long u64x2 __attribute__((ext_vector_type(2), aligned(16)));

// ---------------- workspace layout (bytes) ----------------
static const size_t OFF_CTL   = 0;          // [0]=u64 pfx, [8]=u32 tgt, [12]=u32 count, [16..48)=done[8]
static const size_t OFF_HIST  = 1024;       // 8 passes * 256 * 4 = 8 KB
static const size_t OFF_DOTS  = 1049600;    // 16384*54*4
static const size_t OFF_WCV   = 4588544;    // 589824*4  [tap][ic][oc]
static const size_t OFF_XD    = 6947840;    // 16384*256*4 (conv out f32, HWC)
static const size_t OFF_BOX   = 23725056;   // 147456*16 (float4)
static const size_t OFF_KEYS  = 26084352;   // 147456*8
static const size_t OFF_CKEY  = 27264000;   // 6144*8
static const size_t OFF_CIDX  = 27313152;   // 6144*4
static const size_t OFF_TB    = 27337728;   // 6000*16
static const size_t OFF_TSC   = 27433728;   // 6000*4
static const size_t OFF_ALIVE = 27458048;   // 128*8
static const size_t OFF_FPAD  = 32067584;   // 256*130*132*4 = 17571840  end ~49.6 MB
// paired NMS mask ALIASES featP (featP is dead after conv3x3; nms_mask fully
// rewrites its slots every launch -> replay-deterministic): 6000*128*8 = 6.14MB
static const size_t OFF_MASKP = OFF_FPAD;

// XLA-CPU / Eigen / Cephes f32 exp (FMA form) — bit-matches the np reference.
__device__ __forceinline__ float exp_xla(float x) {
    float m = floorf(__fmaf_rn(x, 1.44269504088896341f, 0.5f));
    float r = __fmaf_rn(m, -0.693359375f, x);
    r = __fmaf_rn(m, 2.12194440e-4f, r);
    float r2 = r * r;
    float p = 1.9875691500e-4f;
    p = __fmaf_rn(p, r, 1.3981999507e-3f);
    p = __fmaf_rn(p, r, 8.3334519073e-3f);
    p = __fmaf_rn(p, r, 4.1665795894e-2f);
    p = __fmaf_rn(p, r, 1.6666665459e-1f);
    p = __fmaf_rn(p, r, 5.0000001201e-1f);
    p = __fmaf_rn(p, r2, r);
    p = __fadd_rn(p, 1.0f);
    int mi = (int)m;
    return p * __int_as_float((mi + 127) << 23);
}

// async global->LDS, 16B per lane, wave-uniform LDS base + lane*16
__device__ __forceinline__ void gload_lds16(const void* g, void* l) {
    __builtin_amdgcn_global_load_lds(
        (const __attribute__((address_space(1))) void*)g,
        (__attribute__((address_space(3))) void*)l, 16, 0, 0);
}

// ---------------- weight prep: rpn_w [oc][ic][tap] -> f32 [tap][ic][oc] ------
__global__ void prep_wcv(const float* __restrict__ rpn_w, float* __restrict__ wcv) {
    int t = blockIdx.x * 256 + threadIdx.x;
    if (t >= 589824) return;
    int tap = t / 65536, rem = t % 65536, ic = rem / 256, oc = rem % 256;
    wcv[t] = rpn_w[oc * 2304 + ic * 9 + tap];
}

// ---------------- feature pad: featP[ic][130][132], +1 halo of literal zeros -
__global__ void prep_pad(const float* __restrict__ feat, float* __restrict__ featP) {
    int t = blockIdx.x * 256 + threadIdx.x;
    if (t >= 256 * 130 * 132) return;
    int ic = t / 17160, rem = t % 17160, y = rem / 132, x = rem % 132;
    int sy = y - 1, sx = x - 1;
    float v = 0.f;
    if (sy >= 0 && sy < 128 && sx >= 0 && sx < 128)
        v = feat[ic * 16384 + sy * 128 + sx];
    featP[t] = v;
}

// ---------------- conv3x3 v4 (PROVEN, R4/R7: 309us): 4px x 8oc per thread ----
// LDS-broadcast weight path (replay-safe; scalar K$ path diverges — R6).
// Per iter: 1 global dwordx4 + 2 LDS broadcast b128 + 32 FMA. Per-output
// chain (tap-major, ic 0..255 ascending, one f32 acc, __fmaf_rn) -> bit-exact.
__global__ __launch_bounds__(256, 2) void conv3x3(const float* __restrict__ featP,
                                                  const float* __restrict__ wcv,
                                                  const float* __restrict__ rpn_b,
                                                  float* __restrict__ xd) {
    __shared__ float sW[8192];                 // [ic][32 oc] for current tap
    const int band = blockIdx.x & 7;           // tile row (XCD-pinned)
    const int slot = blockIdx.x >> 3;          // 0..63
    const int tx = slot & 7, ocb = slot >> 3;  // tile col, oc-block(32)
    const int oc0 = ocb * 32;
    const int tid = threadIdx.x;
    const int wid = tid >> 6;                  // wave 0..3 -> 8 oc each
    const int lane = tid & 63;
    const int py = lane >> 2, px0 = (lane & 3) * 4;   // wave covers 16x16 px
    const int gy = band * 16 + py, gx0 = tx * 16 + px0;
    const int ocB = oc0 + wid * 8;
    float acc[4][8];
#pragma unroll
    for (int p = 0; p < 4; ++p)
#pragma unroll
        for (int o = 0; o < 8; ++o) acc[p][o] = 0.f;
#pragma unroll
    for (int tap = 0; tap < 9; ++tap) {        // k-major: tap (ky,kx)
        __syncthreads();
        for (int idx = tid; idx < 8192; idx += 256)
            sW[idx] = wcv[tap * 65536 + (idx >> 5) * 256 + oc0 + (idx & 31)];
        __syncthreads();
        const float* fp = featP + (size_t)(gy + tap / 3) * 132 + (gx0 + tap % 3);
        const float* wl = sW + wid * 8;        // wave-uniform -> LDS broadcast
#pragma unroll 4
        for (int ic = 0; ic < 256; ++ic) {     // k-minor: ic ascending
            float4a fA = *(const float4a*)(fp + (size_t)ic * 17160);
            float4a w0 = *(const float4a*)(wl + ic * 32);
            float4a w1 = *(const float4a*)(wl + ic * 32 + 4);
#pragma unroll
            for (int p = 0; p < 4; ++p) {
#pragma unroll
                for (int o = 0; o < 4; ++o)
                    acc[p][o] = __fmaf_rn(fA[p], w0[o], acc[p][o]);
#pragma unroll
                for (int o = 0; o < 4; ++o)
                    acc[p][4 + o] = __fmaf_rn(fA[p], w1[o], acc[p][4 + o]);
            }
        }
    }
#pragma unroll
    for (int p = 0; p < 4; ++p) {
        float* op = xd + (size_t)(gy * 128 + gx0 + p) * 256 + ocB;
#pragma unroll
        for (int o = 0; o < 8; ++o) {
            float v = __fadd_rn(acc[p][o], rpn_b[ocB + o]);
            op[o] = v > 0.f ? v : 0.f;
        }
    }
}

// ---------------- heads: 1x1 convs, k=ic sequential f32 FMA (float4 loads) ---
__global__ __launch_bounds__(256, 1) void heads_seq(const float* __restrict__ xd,
                                                    const float* __restrict__ cls_w,
                                                    const float* __restrict__ box_w,
                                                    float* __restrict__ dots) {
    __shared__ float sX[4][260];
    const int tid = threadIdx.x;
    const int pix0 = blockIdx.x * 4;
    for (int idx = tid; idx < 1024; idx += 256)
        sX[idx >> 8][idx & 255] = xd[(size_t)(pix0 + (idx >> 8)) * 256 + (idx & 255)];
    __syncthreads();
    if (tid < 216) {
        const int pl = tid / 54, o = tid % 54;
        const float* wr = (o < 18) ? (cls_w + o * 256) : (box_w + (o - 18) * 256);
        const float4* x4 = (const float4*)&sX[pl][0];
        const float4* w4 = (const float4*)wr;
        float acc = 0.f;
        for (int q = 0; q < 64; ++q) {
            float4 xv = x4[q];
            float4 wv = w4[q];
            acc = __fmaf_rn(xv.x, wv.x, acc);
            acc = __fmaf_rn(xv.y, wv.y, acc);
            acc = __fmaf_rn(xv.z, wv.z, acc);
            acc = __fmaf_rn(xv.w, wv.w, acc);
        }
        dots[(size_t)(pix0 + pl) * 54 + o] = acc;
    }
}

// ---------------- decode: stepwise-F32 softmax + box decode, XLA exp ---------
__global__ __launch_bounds__(256, 1) void decode(const float* __restrict__ dots,
                                                 const float* __restrict__ cls_b,
                                                 const float* __restrict__ box_b,
                                                 float4* __restrict__ boxes,
                                                 u64* __restrict__ keys) {
    const int pix = blockIdx.x * 256 + threadIdx.x;
    if (pix >= 16384) return;
    const float* dt = dots + (size_t)pix * 54;
    float d[54];
#pragma unroll
    for (int i = 0; i < 54; ++i)
        d[i] = __fadd_rn(dt[i], (i < 18 ? cls_b[i] : box_b[i - 18]));
    float m = d[0];
#pragma unroll
    for (int i = 1; i < 18; ++i) m = fmaxf(m, d[i]);
    float e[18];
#pragma unroll
    for (int i = 0; i < 18; ++i) e[i] = exp_xla(__fsub_rn(d[i], m));
    float s = e[0];
#pragma unroll
    for (int i = 1; i < 18; ++i) s = __fadd_rn(s, e[i]);
    const int y = pix >> 7, x = pix & 127;
    const float shx = (float)(x * 32), shy = (float)(y * 32);
    const float AW[9] = {368.f, 736.f, 1472.f, 256.f, 512.f, 1024.f, 176.f, 352.f, 704.f};
    const float AH[9] = {192.f, 384.f, 768.f, 256.f, 512.f, 1024.f, 352.f, 704.f, 1408.f};
#pragma unroll
    for (int a = 0; a < 9; ++a) {
        float score = e[9 + a] / s;
        float wa = AW[a], ha = AH[a];
        float cxa = __fadd_rn(shx, 7.5f), cya = __fadd_rn(shy, 7.5f);
        float dx = d[18 + 4 * a], dyy = d[19 + 4 * a];
        float dw = d[20 + 4 * a], dh = d[21 + 4 * a];
        float cx = __fadd_rn(__fmul_rn(dx, wa), cxa);
        float cy = __fadd_rn(__fmul_rn(dyy, ha), cya);
        float pw = __fmul_rn(wa, exp_xla(dw));
        float ph = __fmul_rn(ha, exp_xla(dh));
        float hx = __fmul_rn(0.5f, pw), hy = __fmul_rn(0.5f, ph);
        float x1 = fminf(fmaxf(__fsub_rn(cx, hx), 0.f), 4095.f);
        float y1 = fminf(fmaxf(__fsub_rn(cy, hy), 0.f), 4095.f);
        float x2 = fminf(fmaxf(__fadd_rn(cx, hx), 0.f), 4095.f);
        float y2 = fminf(fmaxf(__fadd_rn(cy, hy), 0.f), 4095.f);
        float vw = __fadd_rn(__fsub_rn(x2, x1), 1.0f);
        float vh = __fadd_rn(__fsub_rn(y2, y1), 1.0f);
        bool valid = (vw >= 16.0f) && (vh >= 16.0f);
        int i = pix * 9 + a;
        boxes[i] = make_float4(x1, y1, x2, y2);
        u64 k;
        if (valid) {
            u32 b = __float_as_uint(score);
            k = ((u64)(u32)~(b | 0x80000000u) << 32) | (u32)i;
        } else {
            k = (0xFFFFFFFFULL << 32) | (u32)i;
        }
        keys[i] = k;
    }
}

// ---------------- radix select: FUSED hist+scan per pass (last-block-done) ---
// 8 passes of 8 bits. Each pass: 64 blocks build the global hist via
// device-scope atomics; the LAST block (done-counter) re-reads the hist with
// atomic RMWs (coherent across XCDs) and performs the 256-bin scan + boundary
// update in-kernel. Halves radix launch count (16 -> 8).
__global__ __launch_bounds__(256) void hist_scan(const u64* __restrict__ keys,
                                                 u32* __restrict__ ghist,
                                                 u64* pfx, u32* tgt,
                                                 u32* done, int pass) {
    __shared__ u32 lh[256];
    __shared__ u32 lastFlag;
    __shared__ u32 h[256];
    __shared__ u32 incl[256];
    const int t = threadIdx.x;
    lh[t] = 0;
    if (t == 0) lastFlag = 0;
    __syncthreads();
    const u64 pref = *pfx;                 // pass 0: ignored
    const u32 target0 = (pass == 0) ? 6000u : *tgt;
    const int shift = 56 - 8 * pass;
    for (int i = blockIdx.x * 256 + t; i < 147456; i += 64 * 256) {
        u64 k = keys[i];
        bool match = (pass == 0) || ((k >> (shift + 8)) == pref);
        if (match) atomicAdd(&lh[(u32)(k >> shift) & 0xFFu], 1u);
    }
    __syncthreads();
    if (lh[t]) atomicAdd(&ghist[t], lh[t]);
    __threadfence();                       // device fence: hist visible before done++
    __syncthreads();
    if (t == 0) {
        u32 prev = atomicAdd(done, 1u);
        if (prev == 63) lastFlag = 1;
    }
    __syncthreads();
    if (!lastFlag) return;
    // ---- last block: coherent hist read + inclusive scan + boundary ----
    u32 hv = atomicAdd(&ghist[t], 0u);     // atomic RMW read: bypass stale L1/L2
    h[t] = hv;
    incl[t] = hv;
    __syncthreads();
    for (int off = 1; off < 256; off <<= 1) {
        u32 v = (t >= off) ? incl[t - off] : 0u;
        __syncthreads();
        incl[t] += v;
        __syncthreads();
    }
    u64 p0 = (pass == 0) ? 0ULL : pref;
    u32 before = incl[t] - h[t];
    if (before < target0 && target0 <= incl[t]) {
        *pfx = (p0 << 8) | (u64)t;
        *tgt = target0 - before;
    }
}

__global__ void compact(const u64* __restrict__ keys, const u64* __restrict__ kstar,
                        u32* count, u64* __restrict__ ckey, u32* __restrict__ cidx) {
    int i = blockIdx.x * 256 + threadIdx.x;
    if (i >= 147456) return;
    u64 k = keys[i];
    if (k <= *kstar) {
        u32 pos = atomicAdd(count, 1u);
        if (pos < 6144) { ckey[pos] = k; cidx[pos] = (u32)(k & 0xFFFFFFFFu); }
    }
}

// ---------------- exact rank (keys unique) + gather sorted top-6000 ----------
__global__ __launch_bounds__(256) void rank_scatter(const u64* __restrict__ ckey,
                                                    const u32* __restrict__ cidx,
                                                    const u32* __restrict__ count,
                                                    const float4* __restrict__ boxes,
                                                    float4* __restrict__ tb,
                                                    float* __restrict__ tsc) {
    __shared__ u64 LK[6144];
    int N = (int)*count; if (N > 6144) N = 6144;
    for (int i = threadIdx.x; i < N; i += 256) LK[i] = ckey[i];
    __syncthreads();
    int e = blockIdx.x * 256 + threadIdx.x;
    if (e >= N) return;
    u64 myK = LK[e];
    u32 myI = cidx[e];
    int rank = 0;
    for (int c = 0; c < N; ++c) rank += (LK[c] < myK);
    if (rank < 6000) {
        tb[rank] = boxes[myI];
        u32 hi = (u32)(myK >> 32);
        tsc[rank] = (hi == 0xFFFFFFFFu) ? -__builtin_inff()
                                        : __uint_as_float(~hi & 0x7FFFFFFFu);
    }
}

// ---------------- alive bitmask init -----------------------------------------
__global__ void alive_init(const float* __restrict__ tsc, u64* __restrict__ alive0) {
    int r = blockIdx.x * 256 + threadIdx.x;
    bool a = false;
    if (r < 6000) a = tsc[r] > -__builtin_inff();
    u64 b = __ballot(a);
    if ((threadIdx.x & 63) == 0) alive0[r >> 6] = b;
}

// ---------------- suppression bitmask, PAIRED layout -------------------------
// m[j][i] = iou(tb[j],tb[i]) > 0.7. Row j stored as 128 u64: word w lands at
// slot 2*(w&63) + (w>>6), i.e. lane l's pair (word l, word 64+l) is 16B
// contiguous -> nms_seq reads it with ONE ds_read_b128. Row = 1024B = exactly
// one gload_lds16 sweep. Odd slots for l>=30 are never written (consumed only
// under lane<30 in nms_seq) -> poison-safe.
__global__ __launch_bounds__(256) void nms_mask(const float4* __restrict__ tb,
                                                u64* __restrict__ mask) {
    int tid = blockIdx.x * 256 + threadIdx.x;
    if (tid >= 6000 * 94) return;
    int j = tid / 94, w = tid % 94;
    float4 bj = tb[j];
    float arJ = __fmul_rn(__fadd_rn(__fsub_rn(bj.z, bj.x), 1.0f),
                          __fadd_rn(__fsub_rn(bj.w, bj.y), 1.0f));
    u64 m = 0;
    int base = w * 64;
#pragma unroll 4
    for (int b = 0; b < 64; ++b) {
        int i = base + b;
        if (i >= 6000) break;
        float4 bi = tb[i];
        float arI = __fmul_rn(__fadd_rn(__fsub_rn(bi.z, bi.x), 1.0f),
                              __fadd_rn(__fsub_rn(bi.w, bi.y), 1.0f));
        float xx1 = fmaxf(bj.x, bi.x), yy1 = fmaxf(bj.y, bi.y);
        float xx2 = fminf(bj.z, bi.z), yy2 = fminf(bj.w, bi.w);
        float ww = fmaxf(__fadd_rn(__fsub_rn(xx2, xx1), 1.0f), 0.0f);
        float hh = fmaxf(__fadd_rn(__fsub_rn(yy2, yy1), 1.0f), 0.0f);
        float inter = __fmul_rn(ww, hh);
        float uni = __fsub_rn(__fadd_rn(arJ, arI), inter);
        float iou = inter / uni;
        if (iou > 0.7f) m |= (1ULL << b);
    }
    mask[(size_t)j * 128 + 2 * (w & 63) + (w >> 6)] = m;
}

// ---------------- sequential NMS v4: paired rows, dbuf prefetched window -----
// Per selection (window hit): ONE ds_read_b128 gives lane l both row words
// (l, 64+l). Refill: 64 x gload_lds16, one per row (1024B), into the other
// 64KB buffer; prefetch issued without wait right after a window activates.
// Window starts clamped to row 5936 -> all gloads stay inside mask.
__global__ __launch_bounds__(64, 1) void nms_seq(const u64* __restrict__ alive0,
                                                 const u64* __restrict__ mask,
                                                 const float4* __restrict__ tb,
                                                 float* __restrict__ out) {
    __shared__ __align__(16) u64 lwin[2][64 * 128];   // 2 x 64KB windows
    __shared__ u32 sel[1000];
    const int lane = threadIdx.x;
    u64 wl = alive0[lane];
    u64 wh = (lane < 30) ? alive0[64 + lane] : 0ULL;
    int base = -1000000;   // force refill on first selection
    int pbase = -1;        // prefetch window start (-1 = none), in buf[cur^1]
    int cur = 0;
    int k = 0;
    for (; k < 1000; ++k) {
        // ---- j = first alive (strictly increasing across iterations) ----
        int j;
        {
            u64 blo = __ballot(wl != 0ULL);
            if (blo) {
                int l = __ffsll((long long)blo) - 1;
                u32 a = __builtin_amdgcn_readlane((u32)wl, l);
                u32 b = __builtin_amdgcn_readlane((u32)(wl >> 32), l);
                u64 w = ((u64)b << 32) | (u64)a;
                j = l * 64 + __ffsll((long long)w) - 1;
            } else {
                u64 bhi = __ballot(wh != 0ULL);
                if (!bhi) break;  // exhausted: remaining out rows stay 0
                int l = __ffsll((long long)bhi) - 1;
                u32 a = __builtin_amdgcn_readlane((u32)wh, l);
                u32 b = __builtin_amdgcn_readlane((u32)(wh >> 32), l);
                u64 w = ((u64)b << 32) | (u64)a;
                j = (64 + l) * 64 + __ffsll((long long)w) - 1;
            }
        }
        if (lane == 0) sel[k] = (u32)j;
        // ---- window management (wave-uniform branch) ----
        if (j >= base + 64) {
            if (pbase >= 0 && j < pbase + 64) {
                // prefetched buffer covers j: just retire outstanding loads
                asm volatile("s_waitcnt vmcnt(0)" ::: "memory");
                cur ^= 1;
                base = pbase;
            } else {
                // jump past prefetch (or first iter): full refill into cur
                int js = (j > 5936) ? 5936 : j;     // clamp: stay inside mask
                asm volatile("s_waitcnt vmcnt(0)" ::: "memory");
                const char* gsrc = (const char*)mask + (size_t)js * 1024 + (size_t)lane * 16;
                char* ldst = (char*)&lwin[cur][0];
#pragma unroll
                for (int i = 0; i < 64; ++i)
                    gload_lds16(gsrc + (size_t)i * 1024, ldst + i * 1024);
                base = js;
                asm volatile("s_waitcnt vmcnt(0)" ::: "memory");
            }
            pbase = -1;
            if (base + 64 < 6000) {
                // issue prefetch of next window into the other buffer (NO wait)
                int ps = (base + 64 > 5936) ? 5936 : (base + 64);  // clamp
                const char* gs2 = (const char*)mask + (size_t)ps * 1024 + (size_t)lane * 16;
                char* ld2 = (char*)&lwin[cur ^ 1][0];
#pragma unroll
                for (int i = 0; i < 64; ++i)
                    gload_lds16(gs2 + (size_t)i * 1024, ld2 + i * 1024);
                pbase = ps;
            }
        }
        const int s = j - base;
        u64x2 rd = *(const u64x2*)&lwin[cur][(size_t)s * 128 + 2 * lane];
        u64 rl = rd.x;
        u64 rh = rd.y;
        // ---- apply row j (kills j itself via iou==1) ----
        wl &= ~rl;
        if (lane < 30) wh &= ~rh;
    }
    // ---- bulk gather: rois[k] = (0, tb[sel[k]]) — off the serial path ----
    __syncthreads();
    for (int r = lane; r < k; r += 64) {
        int j = (int)sel[r];
        float4 bj = tb[j];
        out[r * 5 + 1] = bj.x;
        out[r * 5 + 2] = bj.y;
        out[r * 5 + 3] = bj.z;
        out[r * 5 + 4] = bj.w;
    }
}

// ---------------- host ----------------
extern "C" void kernel_launch(void* const* d_in, const int* in_sizes, int n_in,
                              void* d_out, int out_size, void* d_ws, size_t ws_size,
                              hipStream_t stream) {
    const float *feat = nullptr, *rpn_w = nullptr, *rpn_b = nullptr;
    const float *cls_w = nullptr, *cls_b = nullptr, *box_w = nullptr, *box_b = nullptr;
    for (int i = 0; i < n_in; ++i) {
        switch (in_sizes[i]) {
            case 4194304: feat  = (const float*)d_in[i]; break;
            case 589824:  rpn_w = (const float*)d_in[i]; break;
            case 256:     rpn_b = (const float*)d_in[i]; break;
            case 4608:    cls_w = (const float*)d_in[i]; break;
            case 18:      cls_b = (const float*)d_in[i]; break;
            case 9216:    box_w = (const float*)d_in[i]; break;
            case 36:      box_b = (const float*)d_in[i]; break;
            default: break;  // image dims hardcoded (4096)
        }
    }

    char* w = (char*)d_ws;
    u64* pfx       = (u64*)(w + OFF_CTL);
    u32* tgt       = (u32*)(w + OFF_CTL + 8);
    u32* ctlCount  = (u32*)(w + OFF_CTL + 12);
    u32* done      = (u32*)(w + OFF_CTL + 16);   // 8 per-pass done counters
    u32* hist      = (u32*)(w + OFF_HIST);
    float* dots    = (float*)(w + OFF_DOTS);
    float* wcv     = (float*)(w + OFF_WCV);
    float* xd      = (float*)(w + OFF_XD);
    float4* boxes  = (float4*)(w + OFF_BOX);
    u64* keys      = (u64*)(w + OFF_KEYS);
    u64* ckey      = (u64*)(w + OFF_CKEY);
    u32* cidx      = (u32*)(w + OFF_CIDX);
    float4* tb     = (float4*)(w + OFF_TB);
    float* tsc     = (float*)(w + OFF_TSC);
    u64* alive0    = (u64*)(w + OFF_ALIVE);
    u64* maskP     = (u64*)(w + OFF_MASKP);      // aliases featP (dead by then)
    float* featP   = (float*)(w + OFF_FPAD);

    hipMemsetAsync(d_ws, 0, OFF_HIST + 8 * 256 * 4, stream);  // ctl + done + 8 hists
    hipMemsetAsync(d_out, 0, (size_t)out_size * sizeof(float), stream);

    prep_wcv<<<2304, 256, 0, stream>>>(rpn_w, wcv);
    prep_pad<<<17160, 256, 0, stream>>>(feat, featP);
    conv3x3<<<512, 256, 0, stream>>>(featP, wcv, rpn_b, xd);
    heads_seq<<<4096, 256, 0, stream>>>(xd, cls_w, box_w, dots);
    decode<<<64, 256, 0, stream>>>(dots, cls_b, box_b, boxes, keys);
    for (int p = 0; p < 8; ++p)
        hist_scan<<<64, 256, 0, stream>>>(keys, hist + p * 256, pfx, tgt, done + p, p);
    compact<<<576, 256, 0, stream>>>(keys, pfx, ctlCount, ckey, cidx);
    rank_scatter<<<24, 256, 0, stream>>>(ckey, cidx, ctlCount, boxes, tb, tsc);
    alive_init<<<24, 256, 0, stream>>>(tsc, alive0);
    nms_mask<<<2204, 256, 0, stream>>>(tb, maskP);
    nms_seq<<<1, 64, 0, stream>>>(alive0, maskP, tb, (float*)d_out);
}

// Round 11
// 888.238 us; speedup vs baseline: 1.4092x; 1.0184x over previous
//
#include <hip/hip_runtime.h>
#include <stdint.h>
#include <math.h>

typedef unsigned long long u64;
typedef unsigned int u32;
typedef float float4a __attribute__((ext_vector_type(4), aligned(4)));
typedef unsigned long long u64x2 __attribute__((ext_vector_type(2), aligned(16)));

// ---------------- workspace layout (bytes) ----------------
static const size_t OFF_CTL   = 0;          // [0]=u64 pfx, [8]=u32 tgt, [12]=u32 count, [16..48)=done[8]
static const size_t OFF_HIST  = 1024;       // 8 passes * 256 * 4 = 8 KB (4 used)
static const size_t OFF_DOTS  = 1049600;    // (unused after decode fusion)
static const size_t OFF_WCV   = 4588544;    // 589824*4  [tap][ic][oc]
static const size_t OFF_XD    = 6947840;    // 16384*256*4 (conv out f32, HWC)
static const size_t OFF_BOX   = 23725056;   // 147456*16 (float4)
static const size_t OFF_KEYS  = 26084352;   // 147456*8
static const size_t OFF_CKEY  = 27264000;   // 6144*8
static const size_t OFF_CIDX  = 27313152;   // 6144*4
static const size_t OFF_TB    = 27337728;   // 6000*16
static const size_t OFF_ALIVE = 27458048;   // 128*8
static const size_t OFF_FPAD  = 32067584;   // 256*130*132*4 = 17571840  end ~49.6 MB
// paired NMS mask ALIASES featP (featP is dead after conv3x3; nms_mask fully
// rewrites its slots every launch -> replay-deterministic): 6000*128*8 = 6.14MB
static const size_t OFF_MASKP = OFF_FPAD;

// XLA-CPU / Eigen / Cephes f32 exp (FMA form) — bit-matches the np reference.
__device__ __forceinline__ float exp_xla(float x) {
    float m = floorf(__fmaf_rn(x, 1.44269504088896341f, 0.5f));
    float r = __fmaf_rn(m, -0.693359375f, x);
    r = __fmaf_rn(m, 2.12194440e-4f, r);
    float r2 = r * r;
    float p = 1.9875691500e-4f;
    p = __fmaf_rn(p, r, 1.3981999507e-3f);
    p = __fmaf_rn(p, r, 8.3334519073e-3f);
    p = __fmaf_rn(p, r, 4.1665795894e-2f);
    p = __fmaf_rn(p, r, 1.6666665459e-1f);
    p = __fmaf_rn(p, r, 5.0000001201e-1f);
    p = __fmaf_rn(p, r2, r);
    p = __fadd_rn(p, 1.0f);
    int mi = (int)m;
    return p * __int_as_float((mi + 127) << 23);
}

// async global->LDS, 16B per lane, wave-uniform LDS base + lane*16
__device__ __forceinline__ void gload_lds16(const void* g, void* l) {
    __builtin_amdgcn_global_load_lds(
        (const __attribute__((address_space(1))) void*)g,
        (__attribute__((address_space(3))) void*)l, 16, 0, 0);
}

// ---------------- weight prep: rpn_w [oc][ic][tap] -> f32 [tap][ic][oc] ------
__global__ void prep_wcv(const float* __restrict__ rpn_w, float* __restrict__ wcv) {
    int t = blockIdx.x * 256 + threadIdx.x;
    if (t >= 589824) return;
    int tap = t / 65536, rem = t % 65536, ic = rem / 256, oc = rem % 256;
    wcv[t] = rpn_w[oc * 2304 + ic * 9 + tap];
}

// ---------------- feature pad: featP[ic][130][132], +1 halo of literal zeros -
__global__ void prep_pad(const float* __restrict__ feat, float* __restrict__ featP) {
    int t = blockIdx.x * 256 + threadIdx.x;
    if (t >= 256 * 130 * 132) return;
    int ic = t / 17160, rem = t % 17160, y = rem / 132, x = rem % 132;
    int sy = y - 1, sx = x - 1;
    float v = 0.f;
    if (sy >= 0 && sy < 128 && sx >= 0 && sx < 128)
        v = feat[ic * 16384 + sy * 128 + sx];
    featP[t] = v;
}

// ---------------- conv3x3 v4 (PROVEN, R4/R7/R10: 309us): 4px x 8oc/thread ----
// LDS-broadcast weight path (replay-safe; scalar K$ path diverges — R6).
// Per iter: 1 global dwordx4 + 2 LDS broadcast b128 + 32 FMA. Per-output
// chain (tap-major, ic 0..255 ascending, one f32 acc, __fmaf_rn) -> bit-exact.
__global__ __launch_bounds__(256, 2) void conv3x3(const float* __restrict__ featP,
                                                  const float* __restrict__ wcv,
                                                  const float* __restrict__ rpn_b,
                                                  float* __restrict__ xd) {
    __shared__ float sW[8192];                 // [ic][32 oc] for current tap
    const int band = blockIdx.x & 7;           // tile row (XCD-pinned)
    const int slot = blockIdx.x >> 3;          // 0..63
    const int tx = slot & 7, ocb = slot >> 3;  // tile col, oc-block(32)
    const int oc0 = ocb * 32;
    const int tid = threadIdx.x;
    const int wid = tid >> 6;                  // wave 0..3 -> 8 oc each
    const int lane = tid & 63;
    const int py = lane >> 2, px0 = (lane & 3) * 4;   // wave covers 16x16 px
    const int gy = band * 16 + py, gx0 = tx * 16 + px0;
    const int ocB = oc0 + wid * 8;
    float acc[4][8];
#pragma unroll
    for (int p = 0; p < 4; ++p)
#pragma unroll
        for (int o = 0; o < 8; ++o) acc[p][o] = 0.f;
#pragma unroll
    for (int tap = 0; tap < 9; ++tap) {        // k-major: tap (ky,kx)
        __syncthreads();
        for (int idx = tid; idx < 8192; idx += 256)
            sW[idx] = wcv[tap * 65536 + (idx >> 5) * 256 + oc0 + (idx & 31)];
        __syncthreads();
        const float* fp = featP + (size_t)(gy + tap / 3) * 132 + (gx0 + tap % 3);
        const float* wl = sW + wid * 8;        // wave-uniform -> LDS broadcast
#pragma unroll 4
        for (int ic = 0; ic < 256; ++ic) {     // k-minor: ic ascending
            float4a fA = *(const float4a*)(fp + (size_t)ic * 17160);
            float4a w0 = *(const float4a*)(wl + ic * 32);
            float4a w1 = *(const float4a*)(wl + ic * 32 + 4);
#pragma unroll
            for (int p = 0; p < 4; ++p) {
#pragma unroll
                for (int o = 0; o < 4; ++o)
                    acc[p][o] = __fmaf_rn(fA[p], w0[o], acc[p][o]);
#pragma unroll
                for (int o = 0; o < 4; ++o)
                    acc[p][4 + o] = __fmaf_rn(fA[p], w1[o], acc[p][4 + o]);
            }
        }
    }
#pragma unroll
    for (int p = 0; p < 4; ++p) {
        float* op = xd + (size_t)(gy * 128 + gx0 + p) * 256 + ocB;
#pragma unroll
        for (int o = 0; o < 8; ++o) {
            float v = __fadd_rn(acc[p][o], rpn_b[ocB + o]);
            op[o] = v > 0.f ? v : 0.f;
        }
    }
}

// ---------------- heads+decode FUSED: 1x1 convs -> softmax -> boxes/keys -----
// Phase A (identical to old heads_seq): 216 threads compute the 4x54 dots of
// this block's 4 pixels into LDS. Phase B (old decode, re-run per anchor
// thread with the IDENTICAL op sequence -> bit-exact): 36 threads (pl,a)
// each recompute the per-pixel softmax chain from LDS and emit box + key.
// Saves the decode launch + the 3.5MB dots round-trip.
__global__ __launch_bounds__(256, 1) void heads_decode(const float* __restrict__ xd,
                                                       const float* __restrict__ cls_w,
                                                       const float* __restrict__ box_w,
                                                       const float* __restrict__ cls_b,
                                                       const float* __restrict__ box_b,
                                                       float4* __restrict__ boxes,
                                                       u64* __restrict__ keys) {
    __shared__ float sX[4][260];
    __shared__ float sD[4][54];
    const int tid = threadIdx.x;
    const int pix0 = blockIdx.x * 4;
    for (int idx = tid; idx < 1024; idx += 256)
        sX[idx >> 8][idx & 255] = xd[(size_t)(pix0 + (idx >> 8)) * 256 + (idx & 255)];
    __syncthreads();
    if (tid < 216) {
        const int pl = tid / 54, o = tid % 54;
        const float* wr = (o < 18) ? (cls_w + o * 256) : (box_w + (o - 18) * 256);
        const float4* x4 = (const float4*)&sX[pl][0];
        const float4* w4 = (const float4*)wr;
        float acc = 0.f;
        for (int q = 0; q < 64; ++q) {
            float4 xv = x4[q];
            float4 wv = w4[q];
            acc = __fmaf_rn(xv.x, wv.x, acc);
            acc = __fmaf_rn(xv.y, wv.y, acc);
            acc = __fmaf_rn(xv.z, wv.z, acc);
            acc = __fmaf_rn(xv.w, wv.w, acc);
        }
        sD[pl][o] = acc;
    }
    __syncthreads();
    if (tid >= 36) return;
    const int pl = tid / 9, a = tid % 9;
    const int pix = pix0 + pl;
    const float* dt = sD[pl];
    float d[54];
#pragma unroll
    for (int i = 0; i < 54; ++i)
        d[i] = __fadd_rn(dt[i], (i < 18 ? cls_b[i] : box_b[i - 18]));
    float m = d[0];
#pragma unroll
    for (int i = 1; i < 18; ++i) m = fmaxf(m, d[i]);
    float e[18];
#pragma unroll
    for (int i = 0; i < 18; ++i) e[i] = exp_xla(__fsub_rn(d[i], m));
    float s = e[0];
#pragma unroll
    for (int i = 1; i < 18; ++i) s = __fadd_rn(s, e[i]);
    const int y = pix >> 7, x = pix & 127;
    const float shx = (float)(x * 32), shy = (float)(y * 32);
    const float AW[9] = {368.f, 736.f, 1472.f, 256.f, 512.f, 1024.f, 176.f, 352.f, 704.f};
    const float AH[9] = {192.f, 384.f, 768.f, 256.f, 512.f, 1024.f, 352.f, 704.f, 1408.f};
    float score = e[9 + a] / s;
    float wa = AW[a], ha = AH[a];
    float cxa = __fadd_rn(shx, 7.5f), cya = __fadd_rn(shy, 7.5f);
    float dx = d[18 + 4 * a], dyy = d[19 + 4 * a];
    float dw = d[20 + 4 * a], dh = d[21 + 4 * a];
    float cx = __fadd_rn(__fmul_rn(dx, wa), cxa);
    float cy = __fadd_rn(__fmul_rn(dyy, ha), cya);
    float pw = __fmul_rn(wa, exp_xla(dw));
    float ph = __fmul_rn(ha, exp_xla(dh));
    float hx = __fmul_rn(0.5f, pw), hy = __fmul_rn(0.5f, ph);
    float x1 = fminf(fmaxf(__fsub_rn(cx, hx), 0.f), 4095.f);
    float y1 = fminf(fmaxf(__fsub_rn(cy, hy), 0.f), 4095.f);
    float x2 = fminf(fmaxf(__fadd_rn(cx, hx), 0.f), 4095.f);
    float y2 = fminf(fmaxf(__fadd_rn(cy, hy), 0.f), 4095.f);
    float vw = __fadd_rn(__fsub_rn(x2, x1), 1.0f);
    float vh = __fadd_rn(__fsub_rn(y2, y1), 1.0f);
    bool valid = (vw >= 16.0f) && (vh >= 16.0f);
    int i = pix * 9 + a;
    boxes[i] = make_float4(x1, y1, x2, y2);
    u64 k;
    if (valid) {
        u32 b = __float_as_uint(score);
        k = ((u64)(u32)~(b | 0x80000000u) << 32) | (u32)i;
    } else {
        k = (0xFFFFFFFFULL << 32) | (u32)i;
    }
    keys[i] = k;
}

// ---------------- radix select: FUSED hist+scan, 4 passes over SCORE word ----
// Low 32 key bits are the anchor index (pure tie-break) — the rank-6000
// boundary needs only the score word. 4 passes give the exact 32-bit score
// boundary; compact's <= test over (k>>32) admits 6000 + (boundary ties)
// entries, within the 6144 slack. Halves the radix dependency chain.
__global__ __launch_bounds__(256) void hist_scan(const u64* __restrict__ keys,
                                                 u32* __restrict__ ghist,
                                                 u64* pfx, u32* tgt,
                                                 u32* done, int pass) {
    __shared__ u32 lh[256];
    __shared__ u32 lastFlag;
    __shared__ u32 h[256];
    __shared__ u32 incl[256];
    const int t = threadIdx.x;
    lh[t] = 0;
    if (t == 0) lastFlag = 0;
    __syncthreads();
    const u64 pref = *pfx;                 // pass 0: ignored
    const u32 target0 = (pass == 0) ? 6000u : *tgt;
    const int shift = 56 - 8 * pass;
    for (int i = blockIdx.x * 256 + t; i < 147456; i += 64 * 256) {
        u64 k = keys[i];
        bool match = (pass == 0) || ((k >> (shift + 8)) == pref);
        if (match) atomicAdd(&lh[(u32)(k >> shift) & 0xFFu], 1u);
    }
    __syncthreads();
    if (lh[t]) atomicAdd(&ghist[t], lh[t]);
    __threadfence();                       // device fence: hist visible before done++
    __syncthreads();
    if (t == 0) {
        u32 prev = atomicAdd(done, 1u);
        if (prev == 63) lastFlag = 1;
    }
    __syncthreads();
    if (!lastFlag) return;
    // ---- last block: coherent hist read + inclusive scan + boundary ----
    u32 hv = atomicAdd(&ghist[t], 0u);     // atomic RMW read: bypass stale L1/L2
    h[t] = hv;
    incl[t] = hv;
    __syncthreads();
    for (int off = 1; off < 256; off <<= 1) {
        u32 v = (t >= off) ? incl[t - off] : 0u;
        __syncthreads();
        incl[t] += v;
        __syncthreads();
    }
    u64 p0 = (pass == 0) ? 0ULL : pref;
    u32 before = incl[t] - h[t];
    if (before < target0 && target0 <= incl[t]) {
        *pfx = (p0 << 8) | (u64)t;
        *tgt = target0 - before;
    }
}

// compact by 32-bit score boundary; also zeroes alive0 (rank_scatter atomicOrs
// into it in the NEXT kernel -> kernel boundary orders the zeroing).
__global__ void compact(const u64* __restrict__ keys, const u64* __restrict__ kstar,
                        u32* count, u64* __restrict__ ckey, u32* __restrict__ cidx,
                        u64* __restrict__ alive0) {
    if (blockIdx.x == 0 && threadIdx.x < 128) alive0[threadIdx.x] = 0ULL;
    int i = blockIdx.x * 256 + threadIdx.x;
    if (i >= 147456) return;
    u64 k = keys[i];
    if ((k >> 32) <= *kstar) {             // kstar = 32-bit score boundary
        u32 pos = atomicAdd(count, 1u);
        if (pos < 6144) { ckey[pos] = k; cidx[pos] = (u32)(k & 0xFFFFFFFFu); }
    }
}

// ---------------- exact rank + gather + FUSED alive bitmask ------------------
// All compacted keys are valid (invalid keys have score word 0xFFFFFFFF >
// boundary), so rank<6000 <=> alive: atomicOr the bit directly. tsc and the
// alive_init launch are gone.
__global__ __launch_bounds__(256) void rank_scatter(const u64* __restrict__ ckey,
                                                    const u32* __restrict__ cidx,
                                                    const u32* __restrict__ count,
                                                    const float4* __restrict__ boxes,
                                                    float4* __restrict__ tb,
                                                    u64* __restrict__ alive0) {
    __shared__ u64 LK[6144];
    int N = (int)*count; if (N > 6144) N = 6144;
    for (int i = threadIdx.x; i < N; i += 256) LK[i] = ckey[i];
    __syncthreads();
    int e = blockIdx.x * 256 + threadIdx.x;
    if (e >= N) return;
    u64 myK = LK[e];
    u32 myI = cidx[e];
    int rank = 0;
    for (int c = 0; c < N; ++c) rank += (LK[c] < myK);
    if (rank < 6000) {
        tb[rank] = boxes[myI];
        atomicOr(&alive0[rank >> 6], 1ULL << (rank & 63));
    }
}

// ---------------- suppression bitmask, PAIRED layout -------------------------
// Row j = 128 u64; word w at slot 2*(w&63)+(w>>6): lane l's pair (l, 64+l)
// is 16B contiguous -> nms_seq reads it with ONE ds_read_b128; row = 1024B =
// one gload_lds16 sweep.
__global__ __launch_bounds__(256) void nms_mask(const float4* __restrict__ tb,
                                                u64* __restrict__ mask) {
    int tid = blockIdx.x * 256 + threadIdx.x;
    if (tid >= 6000 * 94) return;
    int j = tid / 94, w = tid % 94;
    float4 bj = tb[j];
    float arJ = __fmul_rn(__fadd_rn(__fsub_rn(bj.z, bj.x), 1.0f),
                          __fadd_rn(__fsub_rn(bj.w, bj.y), 1.0f));
    u64 m = 0;
    int base = w * 64;
#pragma unroll 4
    for (int b = 0; b < 64; ++b) {
        int i = base + b;
        if (i >= 6000) break;
        float4 bi = tb[i];
        float arI = __fmul_rn(__fadd_rn(__fsub_rn(bi.z, bi.x), 1.0f),
                              __fadd_rn(__fsub_rn(bi.w, bi.y), 1.0f));
        float xx1 = fmaxf(bj.x, bi.x), yy1 = fmaxf(bj.y, bi.y);
        float xx2 = fminf(bj.z, bi.z), yy2 = fminf(bj.w, bi.w);
        float ww = fmaxf(__fadd_rn(__fsub_rn(xx2, xx1), 1.0f), 0.0f);
        float hh = fmaxf(__fadd_rn(__fsub_rn(yy2, yy1), 1.0f), 0.0f);
        float inter = __fmul_rn(ww, hh);
        float uni = __fsub_rn(__fadd_rn(arJ, arI), inter);
        float iou = inter / uni;
        if (iou > 0.7f) m |= (1ULL << b);
    }
    mask[(size_t)j * 128 + 2 * (w & 63) + (w >> 6)] = m;
}

// ---------------- sequential NMS v4: paired rows, dbuf prefetched window -----
__global__ __launch_bounds__(64, 1) void nms_seq(const u64* __restrict__ alive0,
                                                 const u64* __restrict__ mask,
                                                 const float4* __restrict__ tb,
                                                 float* __restrict__ out) {
    __shared__ __align__(16) u64 lwin[2][64 * 128];   // 2 x 64KB windows
    __shared__ u32 sel[1000];
    const int lane = threadIdx.x;
    u64 wl = alive0[lane];
    u64 wh = (lane < 30) ? alive0[64 + lane] : 0ULL;
    int base = -1000000;   // force refill on first selection
    int pbase = -1;        // prefetch window start (-1 = none), in buf[cur^1]
    int cur = 0;
    int k = 0;
    for (; k < 1000; ++k) {
        // ---- j = first alive (strictly increasing across iterations) ----
        int j;
        {
            u64 blo = __ballot(wl != 0ULL);
            if (blo) {
                int l = __ffsll((long long)blo) - 1;
                u32 a = __builtin_amdgcn_readlane((u32)wl, l);
                u32 b = __builtin_amdgcn_readlane((u32)(wl >> 32), l);
                u64 w = ((u64)b << 32) | (u64)a;
                j = l * 64 + __ffsll((long long)w) - 1;
            } else {
                u64 bhi = __ballot(wh != 0ULL);
                if (!bhi) break;  // exhausted: remaining out rows stay 0
                int l = __ffsll((long long)bhi) - 1;
                u32 a = __builtin_amdgcn_readlane((u32)wh, l);
                u32 b = __builtin_amdgcn_readlane((u32)(wh >> 32), l);
                u64 w = ((u64)b << 32) | (u64)a;
                j = (64 + l) * 64 + __ffsll((long long)w) - 1;
            }
        }
        if (lane == 0) sel[k] = (u32)j;
        // ---- window management (wave-uniform branch) ----
        if (j >= base + 64) {
            if (pbase >= 0 && j < pbase + 64) {
                // prefetched buffer covers j: just retire outstanding loads
                asm volatile("s_waitcnt vmcnt(0)" ::: "memory");
                cur ^= 1;
                base = pbase;
            } else {
                // jump past prefetch (or first iter): full refill into cur
                int js = (j > 5936) ? 5936 : j;     // clamp: stay inside mask
                asm volatile("s_waitcnt vmcnt(0)" ::: "memory");
                const char* gsrc = (const char*)mask + (size_t)js * 1024 + (size_t)lane * 16;
                char* ldst = (char*)&lwin[cur][0];
#pragma unroll
                for (int i = 0; i < 64; ++i)
                    gload_lds16(gsrc + (size_t)i * 1024, ldst + i * 1024);
                base = js;
                asm volatile("s_waitcnt vmcnt(0)" ::: "memory");
            }
            pbase = -1;
            if (base + 64 < 6000) {
                // issue prefetch of next window into the other buffer (NO wait)
                int ps = (base + 64 > 5936) ? 5936 : (base + 64);  // clamp
                const char* gs2 = (const char*)mask + (size_t)ps * 1024 + (size_t)lane * 16;
                char* ld2 = (char*)&lwin[cur ^ 1][0];
#pragma unroll
                for (int i = 0; i < 64; ++i)
                    gload_lds16(gs2 + (size_t)i * 1024, ld2 + i * 1024);
                pbase = ps;
            }
        }
        const int s = j - base;
        u64x2 rd = *(const u64x2*)&lwin[cur][(size_t)s * 128 + 2 * lane];
        u64 rl = rd.x;
        u64 rh = rd.y;
        // ---- apply row j (kills j itself via iou==1) ----
        wl &= ~rl;
        if (lane < 30) wh &= ~rh;
    }
    // ---- bulk gather: rois[k] = (0, tb[sel[k]]) — off the serial path ----
    __syncthreads();
    for (int r = lane; r < k; r += 64) {
        int j = (int)sel[r];
        float4 bj = tb[j];
        out[r * 5 + 1] = bj.x;
        out[r * 5 + 2] = bj.y;
        out[r * 5 + 3] = bj.z;
        out[r * 5 + 4] = bj.w;
    }
}

// ---------------- host ----------------
extern "C" void kernel_launch(void* const* d_in, const int* in_sizes, int n_in,
                              void* d_out, int out_size, void* d_ws, size_t ws_size,
                              hipStream_t stream) {
    const float *feat = nullptr, *rpn_w = nullptr, *rpn_b = nullptr;
    const float *cls_w = nullptr, *cls_b = nullptr, *box_w = nullptr, *box_b = nullptr;
    for (int i = 0; i < n_in; ++i) {
        switch (in_sizes[i]) {
            case 4194304: feat  = (const float*)d_in[i]; break;
            case 589824:  rpn_w = (const float*)d_in[i]; break;
            case 256:     rpn_b = (const float*)d_in[i]; break;
            case 4608:    cls_w = (const float*)d_in[i]; break;
            case 18:      cls_b = (const float*)d_in[i]; break;
            case 9216:    box_w = (const float*)d_in[i]; break;
            case 36:      box_b = (const float*)d_in[i]; break;
            default: break;  // image dims hardcoded (4096)
        }
    }

    char* w = (char*)d_ws;
    u64* pfx       = (u64*)(w + OFF_CTL);
    u32* tgt       = (u32*)(w + OFF_CTL + 8);
    u32* ctlCount  = (u32*)(w + OFF_CTL + 12);
    u32* done      = (u32*)(w + OFF_CTL + 16);   // per-pass done counters
    u32* hist      = (u32*)(w + OFF_HIST);
    float* wcv     = (float*)(w + OFF_WCV);
    float* xd      = (float*)(w + OFF_XD);
    float4* boxes  = (float4*)(w + OFF_BOX);
    u64* keys      = (u64*)(w + OFF_KEYS);
    u64* ckey      = (u64*)(w + OFF_CKEY);
    u32* cidx      = (u32*)(w + OFF_CIDX);
    float4* tb     = (float4*)(w + OFF_TB);
    u64* alive0    = (u64*)(w + OFF_ALIVE);
    u64* maskP     = (u64*)(w + OFF_MASKP);      // aliases featP (dead by then)
    float* featP   = (float*)(w + OFF_FPAD);

    hipMemsetAsync(d_ws, 0, OFF_HIST + 8 * 256 * 4, stream);  // ctl + done + hists
    hipMemsetAsync(d_out, 0, (size_t)out_size * sizeof(float), stream);

    prep_wcv<<<2304, 256, 0, stream>>>(rpn_w, wcv);
    prep_pad<<<17160, 256, 0, stream>>>(feat, featP);
    conv3x3<<<512, 256, 0, stream>>>(featP, wcv, rpn_b, xd);
    heads_decode<<<4096, 256, 0, stream>>>(xd, cls_w, box_w, cls_b, box_b, boxes, keys);
    for (int p = 0; p < 4; ++p)
        hist_scan<<<64, 256, 0, stream>>>(keys, hist + p * 256, pfx, tgt, done + p, p);
    compact<<<576, 256, 0, stream>>>(keys, pfx, ctlCount, ckey, cidx, alive0);
    rank_scatter<<<24, 256, 0, stream>>>(ckey, cidx, ctlCount, boxes, tb, alive0);
    nms_mask<<<2204, 256, 0, stream>>>(tb, maskP);
    nms_seq<<<1, 64, 0, stream>>>(alive0, maskP, tb, (float*)d_out);
}

// Round 12
// 875.901 us; speedup vs baseline: 1.4290x; 1.0141x over previous
//
#include <hip/hip_runtime.h>
#include <stdint.h>
#include <math.h>

typedef unsigned long long u64;
typedef unsigned int u32;
typedef float float4a __attribute__((ext_vector_type(4), aligned(4)));
typedef unsigned long long u64x2 __attribute__((ext_vector_type(2), aligned(16)));

// ---------------- workspace layout (bytes) ----------------
static const size_t OFF_CTL   = 0;          // [0]=u64 pfx, [8]=u32 tgt, [12]=u32 count, [16]=u32 done
static const size_t OFF_HIST  = 1024;       // 4 passes * 256 * 4 = 4 KB (8KB zeroed)
static const size_t OFF_WCV   = 4588544;    // 589824*4  [tap][ic][oc]
static const size_t OFF_XD    = 6947840;    // 16384*256*4 (conv out f32, HWC)
static const size_t OFF_BOX   = 23725056;   // 147456*16 (float4)
static const size_t OFF_KEYS  = 26084352;   // 147456*8
static const size_t OFF_CKEY  = 27264000;   // 6144*8
static const size_t OFF_CIDX  = 27313152;   // 6144*4
static const size_t OFF_TB    = 27337728;   // 6000*16
static const size_t OFF_ALIVE = 27458048;   // 128*8
static const size_t OFF_FPAD  = 32067584;   // 256*130*132*4 = 17571840  end ~49.6 MB
// paired NMS mask ALIASES featP (featP is dead after conv3x3; nms_mask fully
// rewrites its slots every launch -> replay-deterministic): 6000*128*8 = 6.14MB
static const size_t OFF_MASKP = OFF_FPAD;

// XLA-CPU / Eigen / Cephes f32 exp (FMA form) — bit-matches the np reference.
__device__ __forceinline__ float exp_xla(float x) {
    float m = floorf(__fmaf_rn(x, 1.44269504088896341f, 0.5f));
    float r = __fmaf_rn(m, -0.693359375f, x);
    r = __fmaf_rn(m, 2.12194440e-4f, r);
    float r2 = r * r;
    float p = 1.9875691500e-4f;
    p = __fmaf_rn(p, r, 1.3981999507e-3f);
    p = __fmaf_rn(p, r, 8.3334519073e-3f);
    p = __fmaf_rn(p, r, 4.1665795894e-2f);
    p = __fmaf_rn(p, r, 1.6666665459e-1f);
    p = __fmaf_rn(p, r, 5.0000001201e-1f);
    p = __fmaf_rn(p, r2, r);
    p = __fadd_rn(p, 1.0f);
    int mi = (int)m;
    return p * __int_as_float((mi + 127) << 23);
}

// async global->LDS, 16B per lane, wave-uniform LDS base + lane*16
__device__ __forceinline__ void gload_lds16(const void* g, void* l) {
    __builtin_amdgcn_global_load_lds(
        (const __attribute__((address_space(1))) void*)g,
        (__attribute__((address_space(3))) void*)l, 16, 0, 0);
}

// ---------------- prep (FUSED): wcv transpose + feature pad ------------------
__global__ void prep_all(const float* __restrict__ rpn_w, float* __restrict__ wcv,
                         const float* __restrict__ feat, float* __restrict__ featP) {
    int b = blockIdx.x;
    if (b < 2304) {
        int t = b * 256 + threadIdx.x;
        if (t >= 589824) return;
        int tap = t / 65536, rem = t % 65536, ic = rem / 256, oc = rem % 256;
        wcv[t] = rpn_w[oc * 2304 + ic * 9 + tap];
    } else {
        int t = (b - 2304) * 256 + threadIdx.x;
        if (t >= 256 * 130 * 132) return;
        int ic = t / 17160, rem = t % 17160, y = rem / 132, x = rem % 132;
        int sy = y - 1, sx = x - 1;
        float v = 0.f;
        if (sy >= 0 && sy < 128 && sx >= 0 && sx < 128)
            v = feat[ic * 16384 + sy * 128 + sx];
        featP[t] = v;
    }
}

// ---------------- conv3x3 v4 (PROVEN, R4/R7/R10: ~310us): 4px x 8oc/thread ---
// LDS-broadcast weight path (replay-safe; scalar K$ path diverges — R6).
// Per iter: 1 global dwordx4 + 2 LDS broadcast b128 + 32 FMA. Per-output
// chain (tap-major, ic 0..255 ascending, one f32 acc, __fmaf_rn) -> bit-exact.
__global__ __launch_bounds__(256, 2) void conv3x3(const float* __restrict__ featP,
                                                  const float* __restrict__ wcv,
                                                  const float* __restrict__ rpn_b,
                                                  float* __restrict__ xd) {
    __shared__ float sW[8192];                 // [ic][32 oc] for current tap
    const int band = blockIdx.x & 7;           // tile row (XCD-pinned)
    const int slot = blockIdx.x >> 3;          // 0..63
    const int tx = slot & 7, ocb = slot >> 3;  // tile col, oc-block(32)
    const int oc0 = ocb * 32;
    const int tid = threadIdx.x;
    const int wid = tid >> 6;                  // wave 0..3 -> 8 oc each
    const int lane = tid & 63;
    const int py = lane >> 2, px0 = (lane & 3) * 4;   // wave covers 16x16 px
    const int gy = band * 16 + py, gx0 = tx * 16 + px0;
    const int ocB = oc0 + wid * 8;
    float acc[4][8];
#pragma unroll
    for (int p = 0; p < 4; ++p)
#pragma unroll
        for (int o = 0; o < 8; ++o) acc[p][o] = 0.f;
#pragma unroll
    for (int tap = 0; tap < 9; ++tap) {        // k-major: tap (ky,kx)
        __syncthreads();
        for (int idx = tid; idx < 8192; idx += 256)
            sW[idx] = wcv[tap * 65536 + (idx >> 5) * 256 + oc0 + (idx & 31)];
        __syncthreads();
        const float* fp = featP + (size_t)(gy + tap / 3) * 132 + (gx0 + tap % 3);
        const float* wl = sW + wid * 8;        // wave-uniform -> LDS broadcast
#pragma unroll 4
        for (int ic = 0; ic < 256; ++ic) {     // k-minor: ic ascending
            float4a fA = *(const float4a*)(fp + (size_t)ic * 17160);
            float4a w0 = *(const float4a*)(wl + ic * 32);
            float4a w1 = *(const float4a*)(wl + ic * 32 + 4);
#pragma unroll
            for (int p = 0; p < 4; ++p) {
#pragma unroll
                for (int o = 0; o < 4; ++o)
                    acc[p][o] = __fmaf_rn(fA[p], w0[o], acc[p][o]);
#pragma unroll
                for (int o = 0; o < 4; ++o)
                    acc[p][4 + o] = __fmaf_rn(fA[p], w1[o], acc[p][4 + o]);
            }
        }
    }
#pragma unroll
    for (int p = 0; p < 4; ++p) {
        float* op = xd + (size_t)(gy * 128 + gx0 + p) * 256 + ocB;
#pragma unroll
        for (int o = 0; o < 8; ++o) {
            float v = __fadd_rn(acc[p][o], rpn_b[ocB + o]);
            op[o] = v > 0.f ? v : 0.f;
        }
    }
}

// ---------------- heads+decode FUSED: 1x1 convs -> softmax -> boxes/keys -----
__global__ __launch_bounds__(256, 1) void heads_decode(const float* __restrict__ xd,
                                                       const float* __restrict__ cls_w,
                                                       const float* __restrict__ box_w,
                                                       const float* __restrict__ cls_b,
                                                       const float* __restrict__ box_b,
                                                       float4* __restrict__ boxes,
                                                       u64* __restrict__ keys) {
    __shared__ float sX[4][260];
    __shared__ float sD[4][54];
    const int tid = threadIdx.x;
    const int pix0 = blockIdx.x * 4;
    for (int idx = tid; idx < 1024; idx += 256)
        sX[idx >> 8][idx & 255] = xd[(size_t)(pix0 + (idx >> 8)) * 256 + (idx & 255)];
    __syncthreads();
    if (tid < 216) {
        const int pl = tid / 54, o = tid % 54;
        const float* wr = (o < 18) ? (cls_w + o * 256) : (box_w + (o - 18) * 256);
        const float4* x4 = (const float4*)&sX[pl][0];
        const float4* w4 = (const float4*)wr;
        float acc = 0.f;
        for (int q = 0; q < 64; ++q) {
            float4 xv = x4[q];
            float4 wv = w4[q];
            acc = __fmaf_rn(xv.x, wv.x, acc);
            acc = __fmaf_rn(xv.y, wv.y, acc);
            acc = __fmaf_rn(xv.z, wv.z, acc);
            acc = __fmaf_rn(xv.w, wv.w, acc);
        }
        sD[pl][o] = acc;
    }
    __syncthreads();
    if (tid >= 36) return;
    const int pl = tid / 9, a = tid % 9;
    const int pix = pix0 + pl;
    const float* dt = sD[pl];
    float d[54];
#pragma unroll
    for (int i = 0; i < 54; ++i)
        d[i] = __fadd_rn(dt[i], (i < 18 ? cls_b[i] : box_b[i - 18]));
    float m = d[0];
#pragma unroll
    for (int i = 1; i < 18; ++i) m = fmaxf(m, d[i]);
    float e[18];
#pragma unroll
    for (int i = 0; i < 18; ++i) e[i] = exp_xla(__fsub_rn(d[i], m));
    float s = e[0];
#pragma unroll
    for (int i = 1; i < 18; ++i) s = __fadd_rn(s, e[i]);
    const int y = pix >> 7, x = pix & 127;
    const float shx = (float)(x * 32), shy = (float)(y * 32);
    const float AW[9] = {368.f, 736.f, 1472.f, 256.f, 512.f, 1024.f, 176.f, 352.f, 704.f};
    const float AH[9] = {192.f, 384.f, 768.f, 256.f, 512.f, 1024.f, 352.f, 704.f, 1408.f};
    float score = e[9 + a] / s;
    float wa = AW[a], ha = AH[a];
    float cxa = __fadd_rn(shx, 7.5f), cya = __fadd_rn(shy, 7.5f);
    float dx = d[18 + 4 * a], dyy = d[19 + 4 * a];
    float dw = d[20 + 4 * a], dh = d[21 + 4 * a];
    float cx = __fadd_rn(__fmul_rn(dx, wa), cxa);
    float cy = __fadd_rn(__fmul_rn(dyy, ha), cya);
    float pw = __fmul_rn(wa, exp_xla(dw));
    float ph = __fmul_rn(ha, exp_xla(dh));
    float hx = __fmul_rn(0.5f, pw), hy = __fmul_rn(0.5f, ph);
    float x1 = fminf(fmaxf(__fsub_rn(cx, hx), 0.f), 4095.f);
    float y1 = fminf(fmaxf(__fsub_rn(cy, hy), 0.f), 4095.f);
    float x2 = fminf(fmaxf(__fadd_rn(cx, hx), 0.f), 4095.f);
    float y2 = fminf(fmaxf(__fadd_rn(cy, hy), 0.f), 4095.f);
    float vw = __fadd_rn(__fsub_rn(x2, x1), 1.0f);
    float vh = __fadd_rn(__fsub_rn(y2, y1), 1.0f);
    bool valid = (vw >= 16.0f) && (vh >= 16.0f);
    int i = pix * 9 + a;
    boxes[i] = make_float4(x1, y1, x2, y2);
    u64 k;
    if (valid) {
        u32 b = __float_as_uint(score);
        k = ((u64)(u32)~(b | 0x80000000u) << 32) | (u32)i;
    } else {
        k = (0xFFFFFFFFULL << 32) | (u32)i;
    }
    keys[i] = k;
}

// ---------------- radix select + compact, SINGLE KERNEL ----------------------
// 4 passes of 8 bits over the score word, then inline compact. Inter-block
// sync per pass: the proven R7 pattern (device atomics + threadfence + done
// counter) iterated — t0 increments done then spins on atomicAdd(done,0)
// until 64*(pass+1); 64 blocks on 256 CUs are always co-resident. After the
// barrier EVERY block redundantly scans the (atomic-RMW-read, XCD-coherent)
// histogram and tracks pfx/target locally — no cross-pass globals. Replaces
// 5 launches (4x hist_scan + compact) with 1.
__global__ __launch_bounds__(256) void radix_compact(const u64* __restrict__ keys,
                                                     u32* __restrict__ ghist,
                                                     u32* done, u32* count,
                                                     u64* __restrict__ ckey,
                                                     u32* __restrict__ cidx,
                                                     u64* __restrict__ alive0) {
    __shared__ u32 lh[256];
    __shared__ u32 sh[256];
    __shared__ u32 incl[256];
    __shared__ u32 bdig, btgt;
    const int t = threadIdx.x;
    if (blockIdx.x == 0 && t < 128) alive0[t] = 0ULL;   // consumed next kernel
    u64 pref = 0;        // uniform across blocks (identical redundant scans)
    u32 target = 6000;
    for (int pass = 0; pass < 4; ++pass) {
        lh[t] = 0;
        __syncthreads();
        const int shift = 56 - 8 * pass;
        for (int i = blockIdx.x * 256 + t; i < 147456; i += 64 * 256) {
            u64 k = keys[i];
            bool match = (pass == 0) || ((k >> (shift + 8)) == pref);
            if (match) atomicAdd(&lh[(u32)(k >> shift) & 0xFFu], 1u);
        }
        __syncthreads();
        if (lh[t]) atomicAdd(&ghist[pass * 256 + t], lh[t]);
        __threadfence();                   // hist visible before done++
        __syncthreads();
        if (t == 0) {
            atomicAdd(done, 1u);
            const u32 need = 64u * (u32)(pass + 1);
            while (atomicAdd(done, 0u) < need) { }   // spin: all 64 co-resident
        }
        __syncthreads();
        u32 hv = atomicAdd(&ghist[pass * 256 + t], 0u);  // coherent RMW read
        sh[t] = hv;
        incl[t] = hv;
        __syncthreads();
        for (int off = 1; off < 256; off <<= 1) {
            u32 v = (t >= off) ? incl[t - off] : 0u;
            __syncthreads();
            incl[t] += v;
            __syncthreads();
        }
        u32 before = incl[t] - sh[t];
        if (before < target && target <= incl[t]) { bdig = (u32)t; btgt = target - before; }
        __syncthreads();
        pref = (pref << 8) | (u64)bdig;
        target = btgt;
    }
    // pref = exact 32-bit score boundary; compact inline (order-independent:
    // rank_scatter ranks by key value). Slack: 6000 + score-word ties <= 6144.
    for (int i = blockIdx.x * 256 + t; i < 147456; i += 64 * 256) {
        u64 k = keys[i];
        if ((k >> 32) <= pref) {
            u32 pos = atomicAdd(count, 1u);
            if (pos < 6144) { ckey[pos] = k; cidx[pos] = (u32)(k & 0xFFFFFFFFu); }
        }
    }
}

// ---------------- exact rank + gather + FUSED alive bitmask ------------------
__global__ __launch_bounds__(256) void rank_scatter(const u64* __restrict__ ckey,
                                                    const u32* __restrict__ cidx,
                                                    const u32* __restrict__ count,
                                                    const float4* __restrict__ boxes,
                                                    float4* __restrict__ tb,
                                                    u64* __restrict__ alive0) {
    __shared__ u64 LK[6144];
    int N = (int)*count; if (N > 6144) N = 6144;
    for (int i = threadIdx.x; i < N; i += 256) LK[i] = ckey[i];
    __syncthreads();
    int e = blockIdx.x * 256 + threadIdx.x;
    if (e >= N) return;
    u64 myK = LK[e];
    u32 myI = cidx[e];
    int rank = 0;
    for (int c = 0; c < N; ++c) rank += (LK[c] < myK);
    if (rank < 6000) {
        tb[rank] = boxes[myI];
        atomicOr(&alive0[rank >> 6], 1ULL << (rank & 63));
    }
}

// ---------------- suppression bitmask, PAIRED layout -------------------------
// Row j = 128 u64; word w at slot 2*(w&63)+(w>>6): lane l's pair (l, 64+l)
// is 16B contiguous -> nms_seq reads it with ONE ds_read_b128; row = 1024B =
// one gload_lds16 sweep.
__global__ __launch_bounds__(256) void nms_mask(const float4* __restrict__ tb,
                                                u64* __restrict__ mask) {
    int tid = blockIdx.x * 256 + threadIdx.x;
    if (tid >= 6000 * 94) return;
    int j = tid / 94, w = tid % 94;
    float4 bj = tb[j];
    float arJ = __fmul_rn(__fadd_rn(__fsub_rn(bj.z, bj.x), 1.0f),
                          __fadd_rn(__fsub_rn(bj.w, bj.y), 1.0f));
    u64 m = 0;
    int base = w * 64;
#pragma unroll 4
    for (int b = 0; b < 64; ++b) {
        int i = base + b;
        if (i >= 6000) break;
        float4 bi = tb[i];
        float arI = __fmul_rn(__fadd_rn(__fsub_rn(bi.z, bi.x), 1.0f),
                              __fadd_rn(__fsub_rn(bi.w, bi.y), 1.0f));
        float xx1 = fmaxf(bj.x, bi.x), yy1 = fmaxf(bj.y, bi.y);
        float xx2 = fminf(bj.z, bi.z), yy2 = fminf(bj.w, bi.w);
        float ww = fmaxf(__fadd_rn(__fsub_rn(xx2, xx1), 1.0f), 0.0f);
        float hh = fmaxf(__fadd_rn(__fsub_rn(yy2, yy1), 1.0f), 0.0f);
        float inter = __fmul_rn(ww, hh);
        float uni = __fsub_rn(__fadd_rn(arJ, arI), inter);
        float iou = inter / uni;
        if (iou > 0.7f) m |= (1ULL << b);
    }
    mask[(size_t)j * 128 + 2 * (w & 63) + (w >> 6)] = m;
}

// ---------------- sequential NMS v4: paired rows, dbuf prefetched window -----
__global__ __launch_bounds__(64, 1) void nms_seq(const u64* __restrict__ alive0,
                                                 const u64* __restrict__ mask,
                                                 const float4* __restrict__ tb,
                                                 float* __restrict__ out) {
    __shared__ __align__(16) u64 lwin[2][64 * 128];   // 2 x 64KB windows
    __shared__ u32 sel[1000];
    const int lane = threadIdx.x;
    u64 wl = alive0[lane];
    u64 wh = (lane < 30) ? alive0[64 + lane] : 0ULL;
    int base = -1000000;   // force refill on first selection
    int pbase = -1;        // prefetch window start (-1 = none), in buf[cur^1]
    int cur = 0;
    int k = 0;
    for (; k < 1000; ++k) {
        // ---- j = first alive (strictly increasing across iterations) ----
        int j;
        {
            u64 blo = __ballot(wl != 0ULL);
            if (blo) {
                int l = __ffsll((long long)blo) - 1;
                u32 a = __builtin_amdgcn_readlane((u32)wl, l);
                u32 b = __builtin_amdgcn_readlane((u32)(wl >> 32), l);
                u64 w = ((u64)b << 32) | (u64)a;
                j = l * 64 + __ffsll((long long)w) - 1;
            } else {
                u64 bhi = __ballot(wh != 0ULL);
                if (!bhi) break;  // exhausted: remaining out rows stay 0
                int l = __ffsll((long long)bhi) - 1;
                u32 a = __builtin_amdgcn_readlane((u32)wh, l);
                u32 b = __builtin_amdgcn_readlane((u32)(wh >> 32), l);
                u64 w = ((u64)b << 32) | (u64)a;
                j = (64 + l) * 64 + __ffsll((long long)w) - 1;
            }
        }
        if (lane == 0) sel[k] = (u32)j;
        // ---- window management (wave-uniform branch) ----
        if (j >= base + 64) {
            if (pbase >= 0 && j < pbase + 64) {
                // prefetched buffer covers j: just retire outstanding loads
                asm volatile("s_waitcnt vmcnt(0)" ::: "memory");
                cur ^= 1;
                base = pbase;
            } else {
                // jump past prefetch (or first iter): full refill into cur
                int js = (j > 5936) ? 5936 : j;     // clamp: stay inside mask
                asm volatile("s_waitcnt vmcnt(0)" ::: "memory");
                const char* gsrc = (const char*)mask + (size_t)js * 1024 + (size_t)lane * 16;
                char* ldst = (char*)&lwin[cur][0];
#pragma unroll
                for (int i = 0; i < 64; ++i)
                    gload_lds16(gsrc + (size_t)i * 1024, ldst + i * 1024);
                base = js;
                asm volatile("s_waitcnt vmcnt(0)" ::: "memory");
            }
            pbase = -1;
            if (base + 64 < 6000) {
                // issue prefetch of next window into the other buffer (NO wait)
                int ps = (base + 64 > 5936) ? 5936 : (base + 64);  // clamp
                const char* gs2 = (const char*)mask + (size_t)ps * 1024 + (size_t)lane * 16;
                char* ld2 = (char*)&lwin[cur ^ 1][0];
#pragma unroll
                for (int i = 0; i < 64; ++i)
                    gload_lds16(gs2 + (size_t)i * 1024, ld2 + i * 1024);
                pbase = ps;
            }
        }
        const int s = j - base;
        u64x2 rd = *(const u64x2*)&lwin[cur][(size_t)s * 128 + 2 * lane];
        u64 rl = rd.x;
        u64 rh = rd.y;
        // ---- apply row j (kills j itself via iou==1) ----
        wl &= ~rl;
        if (lane < 30) wh &= ~rh;
    }
    // ---- bulk gather: rois[k] = (0, tb[sel[k]]) — off the serial path ----
    __syncthreads();
    for (int r = lane; r < k; r += 64) {
        int j = (int)sel[r];
        float4 bj = tb[j];
        out[r * 5 + 1] = bj.x;
        out[r * 5 + 2] = bj.y;
        out[r * 5 + 3] = bj.z;
        out[r * 5 + 4] = bj.w;
    }
}

// ---------------- host ----------------
extern "C" void kernel_launch(void* const* d_in, const int* in_sizes, int n_in,
                              void* d_out, int out_size, void* d_ws, size_t ws_size,
                              hipStream_t stream) {
    const float *feat = nullptr, *rpn_w = nullptr, *rpn_b = nullptr;
    const float *cls_w = nullptr, *cls_b = nullptr, *box_w = nullptr, *box_b = nullptr;
    for (int i = 0; i < n_in; ++i) {
        switch (in_sizes[i]) {
            case 4194304: feat  = (const float*)d_in[i]; break;
            case 589824:  rpn_w = (const float*)d_in[i]; break;
            case 256:     rpn_b = (const float*)d_in[i]; break;
            case 4608:    cls_w = (const float*)d_in[i]; break;
            case 18:      cls_b = (const float*)d_in[i]; break;
            case 9216:    box_w = (const float*)d_in[i]; break;
            case 36:      box_b = (const float*)d_in[i]; break;
            default: break;  // image dims hardcoded (4096)
        }
    }

    char* w = (char*)d_ws;
    u32* ctlCount  = (u32*)(w + OFF_CTL + 12);
    u32* done      = (u32*)(w + OFF_CTL + 16);
    u32* hist      = (u32*)(w + OFF_HIST);
    float* wcv     = (float*)(w + OFF_WCV);
    float* xd      = (float*)(w + OFF_XD);
    float4* boxes  = (float4*)(w + OFF_BOX);
    u64* keys      = (u64*)(w + OFF_KEYS);
    u64* ckey      = (u64*)(w + OFF_CKEY);
    u32* cidx      = (u32*)(w + OFF_CIDX);
    float4* tb     = (float4*)(w + OFF_TB);
    u64* alive0    = (u64*)(w + OFF_ALIVE);
    u64* maskP     = (u64*)(w + OFF_MASKP);      // aliases featP (dead by then)
    float* featP   = (float*)(w + OFF_FPAD);

    hipMemsetAsync(d_ws, 0, OFF_HIST + 8 * 256 * 4, stream);  // ctl + done + hists
    hipMemsetAsync(d_out, 0, (size_t)out_size * sizeof(float), stream);

    prep_all<<<2304 + 17160, 256, 0, stream>>>(rpn_w, wcv, feat, featP);
    conv3x3<<<512, 256, 0, stream>>>(featP, wcv, rpn_b, xd);
    heads_decode<<<4096, 256, 0, stream>>>(xd, cls_w, box_w, cls_b, box_b, boxes, keys);
    radix_compact<<<64, 256, 0, stream>>>(keys, hist, done, ctlCount, ckey, cidx, alive0);
    rank_scatter<<<24, 256, 0, stream>>>(ckey, cidx, ctlCount, boxes, tb, alive0);
    nms_mask<<<2204, 256, 0, stream>>>(tb, maskP);
    nms_seq<<<1, 64, 0, stream>>>(alive0, maskP, tb, (float*)d_out);
}